// Round 5
// baseline (243.146 us; speedup 1.0000x reference)
//
#include <hip/hip_runtime.h>
#include <hip/hip_bf16.h>

typedef short bf16x8 __attribute__((ext_vector_type(8)));
typedef float f32x4 __attribute__((ext_vector_type(4)));

#define EMB 1024
#define NH 16
#define SEQ 2048
#define BATCH 4
#define MROWS (BATCH * SEQ)

static __device__ inline unsigned short f2bf(float f) {
  unsigned u = __float_as_uint(f);
  u += 0x7fffu + ((u >> 16) & 1u);
  return (unsigned short)(u >> 16);
}

static __device__ inline unsigned cvtpk(float lo, float hi) {
  unsigned r;
  asm("v_cvt_pk_bf16_f32 %0, %1, %2" : "=v"(r) : "v"(lo), "v"(hi));
  return r;
}

static __device__ inline void gload16(const void* g, void* l) {
  __builtin_amdgcn_global_load_lds(
      (const __attribute__((address_space(1))) unsigned int*)g,
      (__attribute__((address_space(3))) unsigned int*)l, 16, 0, 0);
}

// ---------------- weight transpose + cast: W[k][n] f32 -> WT[n][k] bf16 ----------------
// z==0 (Wq) additionally folds in 0.125*log2(e) so attention logits are in exp2 domain.
__global__ __launch_bounds__(256) void wtrans_kernel(
    const float* w0, const float* w1, const float* w2, const float* w3,
    unsigned short* o0, unsigned short* o1, unsigned short* o2, unsigned short* o3) {
  __shared__ float t[32][33];
  int z = blockIdx.z;
  const float* W = z == 0 ? w0 : z == 1 ? w1 : z == 2 ? w2 : w3;
  unsigned short* O = z == 0 ? o0 : z == 1 ? o1 : z == 2 ? o2 : o3;
  float sc = (z == 0) ? 0.18033688011112042f : 1.0f;
  int bx = blockIdx.x * 32;  // k block
  int by = blockIdx.y * 32;  // n block
  int tx = threadIdx.x, ty = threadIdx.y;  // (32,8)
#pragma unroll
  for (int j = 0; j < 4; ++j)
    t[ty + j * 8][tx] = W[(size_t)(bx + ty + j * 8) * EMB + by + tx];
  __syncthreads();
#pragma unroll
  for (int j = 0; j < 4; ++j)
    O[(size_t)(by + ty + j * 8) * EMB + bx + tx] = f2bf(t[tx][ty + j * 8] * sc);
}

// ---------------- GEMM: C[M=8192][N=1024] = A[M][K=1024] * BT[N][K]^T ----------------
template <int IN_F32, int OUT_MODE>
__global__ __launch_bounds__(256) void gemm_kernel(const void* Ap, const unsigned short* Bt, void* Cp) {
  __shared__ __align__(16) unsigned short As[128 * 64];  // XOR-swizzled cols
  __shared__ __align__(16) unsigned short Bs[128 * 64];
  const int K = EMB;
  int tid = threadIdx.x;
  int lane = tid & 63, wave = tid >> 6;
  int q = lane & 15, g = lane >> 4;
  int qx7 = q & 7;
  int wm = (wave >> 1) * 64, wn = (wave & 1) * 64;
  int lin = blockIdx.x + (blockIdx.y << 3);
  int idx = (lin & 7) * 64 + (lin >> 3);
  int tm = (idx >> 3) * 128, tn = (idx & 7) * 128;
  f32x4 acc[4][4] = {};
  for (int kt = 0; kt < K; kt += 64) {
    if (IN_F32) {
      const float* A = (const float*)Ap;
#pragma unroll
      for (int it = 0; it < 4; ++it) {
        int gid = tid + it * 256;
        int row = gid >> 3, cb = gid & 7;
        const float4* s0 = (const float4*)(A + (size_t)(tm + row) * K + kt + cb * 8);
        float4 x = s0[0], y = s0[1];
        uint4 w;
        w.x = cvtpk(x.x, x.y); w.y = cvtpk(x.z, x.w);
        w.z = cvtpk(y.x, y.y); w.w = cvtpk(y.z, y.w);
        *(uint4*)&As[row * 64 + 8 * (cb ^ (row & 7))] = w;
      }
    } else {
      const unsigned short* A = (const unsigned short*)Ap;
#pragma unroll
      for (int it = 0; it < 4; ++it) {
        int gid = tid + it * 256;
        int row = gid >> 3, cb = gid & 7;
        gload16(A + (size_t)(tm + row) * K + kt + 8 * (cb ^ (row & 7)), &As[gid * 8]);
      }
    }
#pragma unroll
    for (int it = 0; it < 4; ++it) {
      int gid = tid + it * 256;
      int row = gid >> 3, cb = gid & 7;
      gload16(Bt + (size_t)(tn + row) * K + kt + 8 * (cb ^ (row & 7)), &Bs[gid * 8]);
    }
    __syncthreads();
#pragma unroll
    for (int s = 0; s < 2; ++s) {
      bf16x8 af[4], bfr[4];
#pragma unroll
      for (int mf = 0; mf < 4; ++mf)
        af[mf] = *(const bf16x8*)&As[(wm + mf * 16 + q) * 64 + 8 * ((4 * s + g) ^ qx7)];
#pragma unroll
      for (int nf = 0; nf < 4; ++nf)
        bfr[nf] = *(const bf16x8*)&Bs[(wn + nf * 16 + q) * 64 + 8 * ((4 * s + g) ^ qx7)];
#pragma unroll
      for (int mf = 0; mf < 4; ++mf)
#pragma unroll
        for (int nf = 0; nf < 4; ++nf)
          acc[mf][nf] = __builtin_amdgcn_mfma_f32_16x16x32_bf16(af[mf], bfr[nf], acc[mf][nf], 0, 0, 0);
    }
    __syncthreads();
  }
  if (OUT_MODE == 0) {
    unsigned short* C = (unsigned short*)Cp;
#pragma unroll
    for (int mf = 0; mf < 4; ++mf)
#pragma unroll
      for (int nf = 0; nf < 4; ++nf)
#pragma unroll
        for (int r = 0; r < 4; ++r) {
          int row = tm + wm + mf * 16 + 4 * g + r;
          int col = tn + wn + nf * 16 + q;
          C[(size_t)row * EMB + col] = f2bf(acc[mf][nf][r]);
        }
  } else if (OUT_MODE == 1) {
    unsigned short* C = (unsigned short*)Cp;
#pragma unroll
    for (int mf = 0; mf < 4; ++mf) {
      int m0 = tm + wm + mf * 16 + 4 * g;
      int b = m0 >> 11, l = m0 & 2047;
#pragma unroll
      for (int nf = 0; nf < 4; ++nf) {
        int n = tn + wn + nf * 16 + q;
        int h = n >> 6, dv = n & 63;
        uint2 w;
        w.x = cvtpk(acc[mf][nf][0], acc[mf][nf][1]);
        w.y = cvtpk(acc[mf][nf][2], acc[mf][nf][3]);
        *(uint2*)&C[(((size_t)b * NH + h) * 64 + dv) * SEQ + l] = w;
      }
    }
  } else {
    float* C = (float*)Cp;
#pragma unroll
    for (int mf = 0; mf < 4; ++mf)
#pragma unroll
      for (int nf = 0; nf < 4; ++nf)
#pragma unroll
        for (int r = 0; r < 4; ++r) {
          int row = tm + wm + mf * 16 + 4 * g + r;
          int col = tn + wn + nf * 16 + q;
          C[(size_t)row * EMB + col] = acc[mf][nf][r];
        }
  }
}

// ---------------- flash attention: merged dual-chunk, R3-exact online softmax ----------------
// Q,K bf16 [b][l][h*64+d] (Q pre-scaled by 0.125*log2e); VT bf16 [b][h][dv][l]; out bf16.
// Block px handles q-chunks cA=px and cB=31-px over a SINGLE shared kv-tile loop:
// K/V LDS fragments are read once and feed both chunks' MFMAs.
__global__ __launch_bounds__(256) void attn_kernel(
    const unsigned short* Qb, const unsigned short* Kb, const unsigned short* VTb,
    const int* pad, unsigned short* Ob) {
  __shared__ __align__(16) unsigned short Ks[2][64 * 64];   // [kv][d], src-XOR-swizzled
  __shared__ __align__(16) unsigned short Vs[2][64 * 64];   // [dv][kv], src-XOR-swizzled
  __shared__ __align__(16) unsigned short PsA[4][16 * 64];  // per-wave P, XOR-swizzled
  __shared__ __align__(16) unsigned short PsB[4][16 * 64];
  int tid = threadIdx.x;
  int lane = tid & 63, wave = tid >> 6;
  int q = lane & 15, g = lane >> 4;
  int qx7 = q & 7;
  // XCD-chunked swizzle: 16 blocks of one (b,h) share an XCD L2
  int lin = blockIdx.x;
  int idx = (lin & 7) * 128 + (lin >> 3);
  int b = idx >> 8, h = (idx >> 4) & 15, px = idx & 15;
  int cA = px, cB = 31 - px;  // cA < cB always
  int qgA = cA * 64 + wave * 16 + q;
  int qgB = cB * 64 + wave * 16 + q;

  const unsigned short* QrowA = Qb + ((size_t)(b * SEQ + qgA)) * EMB + h * 64;
  const unsigned short* QrowB = Qb + ((size_t)(b * SEQ + qgB)) * EMB + h * 64;
  bf16x8 qfA0 = *(const bf16x8*)(QrowA + 8 * g);
  bf16x8 qfA1 = *(const bf16x8*)(QrowA + 32 + 8 * g);
  bf16x8 qfB0 = *(const bf16x8*)(QrowB + 8 * g);
  bf16x8 qfB1 = *(const bf16x8*)(QrowB + 32 + 8 * g);

  f32x4 oA[4] = {}, oB[4] = {};
  float mA = -INFINITY, lA = 0.f, mB = -INFINITY, lB = 0.f;

  int srow = tid >> 3, scb = tid & 7;
  int ssw = 8 * (scb ^ (srow & 7));
  const unsigned short* Kbase = Kb + (size_t)b * SEQ * EMB + (size_t)srow * EMB + h * 64 + ssw;
  const unsigned short* Vbase = VTb + (((size_t)(b * NH + h)) * 64 + srow) * SEQ + ssw;

  // prologue: stage tile 0 into buf 0
#pragma unroll
  for (int it = 0; it < 2; ++it) {
    gload16(Kbase + (size_t)(it * 32) * EMB, &Ks[0][(tid + it * 256) * 8]);
    gload16(Vbase + (size_t)(it * 32) * SEQ, &Vs[0][(tid + it * 256) * 8]);
  }
  __syncthreads();

#pragma unroll 1
  for (int t = 0; t <= cB; ++t) {
    int kvt = t * 64;
    int cur = t & 1;
    if (t < cB) {
#pragma unroll
      for (int it = 0; it < 2; ++it) {
        gload16(Kbase + (size_t)(kvt + 64 + it * 32) * EMB, &Ks[cur ^ 1][(tid + it * 256) * 8]);
        gload16(Vbase + (size_t)(kvt + 64) + (size_t)(it * 32) * SEQ, &Vs[cur ^ 1][(tid + it * 256) * 8]);
      }
    }
    int pv = pad[b * SEQ + kvt + lane];
    unsigned long long pmask = __ballot(pv != 0);
    bool doA = (t <= cA);

    // ---- QK for both chunks, shared K fragments ----
    f32x4 sfA[4] = {}, sfB[4] = {};
    __builtin_amdgcn_s_setprio(1);
#pragma unroll
    for (int s = 0; s < 2; ++s) {
#pragma unroll
      for (int mf = 0; mf < 4; ++mf) {
        bf16x8 kf = *(const bf16x8*)&Ks[cur][(mf * 16 + q) * 64 + 8 * ((4 * s + g) ^ qx7)];
        if (doA) sfA[mf] = __builtin_amdgcn_mfma_f32_16x16x32_bf16(kf, s ? qfA1 : qfA0, sfA[mf], 0, 0, 0);
        sfB[mf] = __builtin_amdgcn_mfma_f32_16x16x32_bf16(kf, s ? qfB1 : qfB0, sfB[mf], 0, 0, 0);
      }
    }
    __builtin_amdgcn_s_setprio(0);

    // ---- softmax chunk A (R3-exact) ----
    if (doA) {
      float tmax = -INFINITY;
      bool full = (t < cA) && (pmask == ~0ull);
      if (full) {
#pragma unroll
        for (int mf = 0; mf < 4; ++mf)
#pragma unroll
          for (int r = 0; r < 4; ++r) tmax = fmaxf(tmax, sfA[mf][r]);
      } else {
#pragma unroll
        for (int mf = 0; mf < 4; ++mf)
#pragma unroll
          for (int r = 0; r < 4; ++r) {
            int kvl = mf * 16 + 4 * g + r;
            bool keep = (kvt + kvl <= qgA) && ((pmask >> kvl) & 1ULL);
            float sv = keep ? sfA[mf][r] : -INFINITY;
            sfA[mf][r] = sv;
            tmax = fmaxf(tmax, sv);
          }
      }
      tmax = fmaxf(tmax, __shfl_xor(tmax, 16));
      tmax = fmaxf(tmax, __shfl_xor(tmax, 32));
      if (!__all(tmax <= mA + 8.0f)) {
        float m_new = fmaxf(mA, tmax);
        float alpha = __builtin_amdgcn_exp2f(mA - m_new);
        lA *= alpha;
#pragma unroll
        for (int mv = 0; mv < 4; ++mv) oA[mv] *= alpha;
        mA = m_new;
      }
      float rsum = 0.f;
      float pv0[16];
#pragma unroll
      for (int mf = 0; mf < 4; ++mf)
#pragma unroll
        for (int r = 0; r < 4; ++r) {
          float p = __builtin_amdgcn_exp2f(sfA[mf][r] - mA);
          pv0[mf * 4 + r] = p;
          rsum += p;
        }
#pragma unroll
      for (int mf = 0; mf < 4; ++mf) {
        uint2 w;
        w.x = cvtpk(pv0[mf * 4 + 0], pv0[mf * 4 + 1]);
        w.y = cvtpk(pv0[mf * 4 + 2], pv0[mf * 4 + 3]);
        int cbP = 2 * mf + (g >> 1);
        *(uint2*)&PsA[wave][q * 64 + 8 * (cbP ^ qx7) + 4 * (g & 1)] = w;
      }
      rsum += __shfl_xor(rsum, 16);
      rsum += __shfl_xor(rsum, 32);
      lA += rsum;
    }

    // ---- softmax chunk B (R3-exact) ----
    {
      float tmax = -INFINITY;
      bool full = (t < cB) && (pmask == ~0ull);
      if (full) {
#pragma unroll
        for (int mf = 0; mf < 4; ++mf)
#pragma unroll
          for (int r = 0; r < 4; ++r) tmax = fmaxf(tmax, sfB[mf][r]);
      } else {
#pragma unroll
        for (int mf = 0; mf < 4; ++mf)
#pragma unroll
          for (int r = 0; r < 4; ++r) {
            int kvl = mf * 16 + 4 * g + r;
            bool keep = (kvt + kvl <= qgB) && ((pmask >> kvl) & 1ULL);
            float sv = keep ? sfB[mf][r] : -INFINITY;
            sfB[mf][r] = sv;
            tmax = fmaxf(tmax, sv);
          }
      }
      tmax = fmaxf(tmax, __shfl_xor(tmax, 16));
      tmax = fmaxf(tmax, __shfl_xor(tmax, 32));
      if (!__all(tmax <= mB + 8.0f)) {
        float m_new = fmaxf(mB, tmax);
        float alpha = __builtin_amdgcn_exp2f(mB - m_new);
        lB *= alpha;
#pragma unroll
        for (int mv = 0; mv < 4; ++mv) oB[mv] *= alpha;
        mB = m_new;
      }
      float rsum = 0.f;
      float pv1[16];
#pragma unroll
      for (int mf = 0; mf < 4; ++mf)
#pragma unroll
        for (int r = 0; r < 4; ++r) {
          float p = __builtin_amdgcn_exp2f(sfB[mf][r] - mB);
          pv1[mf * 4 + r] = p;
          rsum += p;
        }
#pragma unroll
      for (int mf = 0; mf < 4; ++mf) {
        uint2 w;
        w.x = cvtpk(pv1[mf * 4 + 0], pv1[mf * 4 + 1]);
        w.y = cvtpk(pv1[mf * 4 + 2], pv1[mf * 4 + 3]);
        int cbP = 2 * mf + (g >> 1);
        *(uint2*)&PsB[wave][q * 64 + 8 * (cbP ^ qx7) + 4 * (g & 1)] = w;
      }
      rsum += __shfl_xor(rsum, 16);
      rsum += __shfl_xor(rsum, 32);
      lB += rsum;
    }

    // ---- PV for both chunks, shared V fragments ----
    __builtin_amdgcn_s_setprio(1);
#pragma unroll
    for (int s = 0; s < 2; ++s) {
      bf16x8 pbA = *(const bf16x8*)&PsA[wave][q * 64 + 8 * ((4 * s + g) ^ qx7)];
      bf16x8 pbB = *(const bf16x8*)&PsB[wave][q * 64 + 8 * ((4 * s + g) ^ qx7)];
#pragma unroll
      for (int mv = 0; mv < 4; ++mv) {
        bf16x8 va = *(const bf16x8*)&Vs[cur][(mv * 16 + q) * 64 + 8 * ((4 * s + g) ^ qx7)];
        if (doA) oA[mv] = __builtin_amdgcn_mfma_f32_16x16x32_bf16(va, pbA, oA[mv], 0, 0, 0);
        oB[mv] = __builtin_amdgcn_mfma_f32_16x16x32_bf16(va, pbB, oB[mv], 0, 0, 0);
      }
    }
    __builtin_amdgcn_s_setprio(0);
    __syncthreads();  // publishes next buf, protects cur for overwrite at t+2
  }

  float invA = 1.0f / lA;
  float invB = 1.0f / lB;
  unsigned short* OrowA = Ob + ((size_t)(b * SEQ + qgA)) * EMB + h * 64;
  unsigned short* OrowB = Ob + ((size_t)(b * SEQ + qgB)) * EMB + h * 64;
#pragma unroll
  for (int mv = 0; mv < 4; ++mv) {
    uint2 wa, wb;
    wa.x = cvtpk(oA[mv][0] * invA, oA[mv][1] * invA);
    wa.y = cvtpk(oA[mv][2] * invA, oA[mv][3] * invA);
    wb.x = cvtpk(oB[mv][0] * invB, oB[mv][1] * invB);
    wb.y = cvtpk(oB[mv][2] * invB, oB[mv][3] * invB);
    *(uint2*)&OrowA[mv * 16 + 4 * g] = wa;
    *(uint2*)&OrowB[mv * 16 + 4 * g] = wb;
  }
}

extern "C" void kernel_launch(void* const* d_in, const int* in_sizes, int n_in,
                              void* d_out, int out_size, void* d_ws, size_t ws_size,
                              hipStream_t stream) {
  const float* query = (const float*)d_in[0];
  const float* key   = (const float*)d_in[1];
  const float* value = (const float*)d_in[2];
  const int*   pad   = (const int*)d_in[3];
  const float* Wq = (const float*)d_in[4];
  const float* Wk = (const float*)d_in[5];
  const float* Wv = (const float*)d_in[6];
  const float* Wo = (const float*)d_in[7];

  unsigned short* WqT = (unsigned short*)d_ws;
  unsigned short* WkT = WqT + (size_t)EMB * EMB;
  unsigned short* WvT = WkT + (size_t)EMB * EMB;
  unsigned short* WoT = WvT + (size_t)EMB * EMB;
  unsigned short* Qb  = WoT + (size_t)EMB * EMB;
  unsigned short* Kb  = Qb + (size_t)MROWS * EMB;
  unsigned short* VTb = Kb + (size_t)MROWS * EMB;
  unsigned short* Ab  = VTb + (size_t)MROWS * EMB;

  wtrans_kernel<<<dim3(EMB / 32, EMB / 32, 4), dim3(32, 8), 0, stream>>>(
      Wq, Wk, Wv, Wo, WqT, WkT, WvT, WoT);
  gemm_kernel<1, 0><<<dim3(8, 64), 256, 0, stream>>>(query, WqT, Qb);
  gemm_kernel<1, 0><<<dim3(8, 64), 256, 0, stream>>>(key, WkT, Kb);
  gemm_kernel<1, 1><<<dim3(8, 64), 256, 0, stream>>>(value, WvT, VTb);
  attn_kernel<<<dim3(1024), 256, 0, stream>>>(Qb, Kb, VTb, pad, Ab);
  gemm_kernel<0, 2><<<dim3(8, 64), 256, 0, stream>>>(Ab, WoT, d_out);
}

// Round 6
// 219.750 us; speedup vs baseline: 1.1065x; 1.1065x over previous
//
#include <hip/hip_runtime.h>
#include <hip/hip_bf16.h>

typedef short bf16x8 __attribute__((ext_vector_type(8)));
typedef float f32x4 __attribute__((ext_vector_type(4)));

#define EMB 1024
#define NH 16
#define SEQ 2048
#define BATCH 4
#define MROWS (BATCH * SEQ)

static __device__ inline unsigned short f2bf(float f) {
  unsigned u = __float_as_uint(f);
  u += 0x7fffu + ((u >> 16) & 1u);
  return (unsigned short)(u >> 16);
}

static __device__ inline unsigned cvtpk(float lo, float hi) {
  unsigned r;
  asm("v_cvt_pk_bf16_f32 %0, %1, %2" : "=v"(r) : "v"(lo), "v"(hi));
  return r;
}

static __device__ inline void gload16(const void* g, void* l) {
  __builtin_amdgcn_global_load_lds(
      (const __attribute__((address_space(1))) unsigned int*)g,
      (__attribute__((address_space(3))) unsigned int*)l, 16, 0, 0);
}

// ---------------- weight transpose + cast: W[k][n] f32 -> WT[n][k] bf16 ----------------
// z==0 (Wq) additionally folds in 0.125*log2(e) so attention logits are in exp2 domain.
__global__ __launch_bounds__(256) void wtrans_kernel(
    const float* w0, const float* w1, const float* w2, const float* w3,
    unsigned short* o0, unsigned short* o1, unsigned short* o2, unsigned short* o3) {
  __shared__ float t[32][33];
  int z = blockIdx.z;
  const float* W = z == 0 ? w0 : z == 1 ? w1 : z == 2 ? w2 : w3;
  unsigned short* O = z == 0 ? o0 : z == 1 ? o1 : z == 2 ? o2 : o3;
  float sc = (z == 0) ? 0.18033688011112042f : 1.0f;
  int bx = blockIdx.x * 32;  // k block
  int by = blockIdx.y * 32;  // n block
  int tx = threadIdx.x, ty = threadIdx.y;  // (32,8)
#pragma unroll
  for (int j = 0; j < 4; ++j)
    t[ty + j * 8][tx] = W[(size_t)(bx + ty + j * 8) * EMB + by + tx];
  __syncthreads();
#pragma unroll
  for (int j = 0; j < 4; ++j)
    O[(size_t)(by + ty + j * 8) * EMB + bx + tx] = f2bf(t[tx][ty + j * 8] * sc);
}

// ---------------- merged QKV projection GEMM ----------------
// z=0: Q = query*WqT (bf16 [m][n]); z=1: K = key*WkT; z=2: V = value*WvT, V-transposed out.
__global__ __launch_bounds__(256) void qkv_gemm(
    const float* qry, const float* key, const float* val,
    const unsigned short* WqT, const unsigned short* WkT, const unsigned short* WvT,
    unsigned short* Qb, unsigned short* Kb, unsigned short* VTb) {
  __shared__ __align__(16) unsigned short As[128 * 64];  // XOR-swizzled cols
  __shared__ __align__(16) unsigned short Bs[128 * 64];
  const int K = EMB;
  int z = blockIdx.z;
  const float* A = z == 0 ? qry : z == 1 ? key : val;
  const unsigned short* Bt = z == 0 ? WqT : z == 1 ? WkT : WvT;
  int tid = threadIdx.x;
  int lane = tid & 63, wave = tid >> 6;
  int q = lane & 15, g = lane >> 4;
  int qx7 = q & 7;
  int wm = (wave >> 1) * 64, wn = (wave & 1) * 64;
  int lin = blockIdx.x + (blockIdx.y << 3);
  int idx = (lin & 7) * 64 + (lin >> 3);
  int tm = (idx >> 3) * 128, tn = (idx & 7) * 128;
  f32x4 acc[4][4] = {};
  for (int kt = 0; kt < K; kt += 64) {
#pragma unroll
    for (int it = 0; it < 4; ++it) {
      int gid = tid + it * 256;
      int row = gid >> 3, cb = gid & 7;
      const float4* s0 = (const float4*)(A + (size_t)(tm + row) * K + kt + cb * 8);
      float4 x = s0[0], y = s0[1];
      uint4 w;
      w.x = cvtpk(x.x, x.y); w.y = cvtpk(x.z, x.w);
      w.z = cvtpk(y.x, y.y); w.w = cvtpk(y.z, y.w);
      *(uint4*)&As[row * 64 + 8 * (cb ^ (row & 7))] = w;
    }
#pragma unroll
    for (int it = 0; it < 4; ++it) {
      int gid = tid + it * 256;
      int row = gid >> 3, cb = gid & 7;
      gload16(Bt + (size_t)(tn + row) * K + kt + 8 * (cb ^ (row & 7)), &Bs[gid * 8]);
    }
    __syncthreads();
#pragma unroll
    for (int s = 0; s < 2; ++s) {
      bf16x8 af[4], bfr[4];
#pragma unroll
      for (int mf = 0; mf < 4; ++mf)
        af[mf] = *(const bf16x8*)&As[(wm + mf * 16 + q) * 64 + 8 * ((4 * s + g) ^ qx7)];
#pragma unroll
      for (int nf = 0; nf < 4; ++nf)
        bfr[nf] = *(const bf16x8*)&Bs[(wn + nf * 16 + q) * 64 + 8 * ((4 * s + g) ^ qx7)];
#pragma unroll
      for (int mf = 0; mf < 4; ++mf)
#pragma unroll
        for (int nf = 0; nf < 4; ++nf)
          acc[mf][nf] = __builtin_amdgcn_mfma_f32_16x16x32_bf16(af[mf], bfr[nf], acc[mf][nf], 0, 0, 0);
    }
    __syncthreads();
  }
  if (z != 2) {
    unsigned short* C = z == 0 ? Qb : Kb;
#pragma unroll
    for (int mf = 0; mf < 4; ++mf)
#pragma unroll
      for (int nf = 0; nf < 4; ++nf) {
        int row = tm + wm + mf * 16 + 4 * g;
        int col = tn + wn + nf * 16 + q;
        uint2 w;
        w.x = cvtpk(acc[mf][nf][0], acc[mf][nf][1]);
        w.y = cvtpk(acc[mf][nf][2], acc[mf][nf][3]);
        // rows 4g..4g+3 are consecutive in m; write 4 scalar bf16 (strided by EMB)
        C[(size_t)(row + 0) * EMB + col] = (unsigned short)(w.x & 0xffff);
        C[(size_t)(row + 1) * EMB + col] = (unsigned short)(w.x >> 16);
        C[(size_t)(row + 2) * EMB + col] = (unsigned short)(w.y & 0xffff);
        C[(size_t)(row + 3) * EMB + col] = (unsigned short)(w.y >> 16);
      }
  } else {
    unsigned short* C = VTb;
#pragma unroll
    for (int mf = 0; mf < 4; ++mf) {
      int m0 = tm + wm + mf * 16 + 4 * g;
      int b = m0 >> 11, l = m0 & 2047;
#pragma unroll
      for (int nf = 0; nf < 4; ++nf) {
        int n = tn + wn + nf * 16 + q;
        int h = n >> 6, dv = n & 63;
        uint2 w;
        w.x = cvtpk(acc[mf][nf][0], acc[mf][nf][1]);
        w.y = cvtpk(acc[mf][nf][2], acc[mf][nf][3]);
        *(uint2*)&C[(((size_t)b * NH + h) * 64 + dv) * SEQ + l] = w;
      }
    }
  }
}

// ---------------- final GEMM: out[M][1024] f32 = Ab[M][1024] * WoT^T ----------------
__global__ __launch_bounds__(256) void out_gemm(const unsigned short* Ab, const unsigned short* Bt, float* Cp) {
  __shared__ __align__(16) unsigned short As[128 * 64];
  __shared__ __align__(16) unsigned short Bs[128 * 64];
  const int K = EMB;
  int tid = threadIdx.x;
  int lane = tid & 63, wave = tid >> 6;
  int q = lane & 15, g = lane >> 4;
  int qx7 = q & 7;
  int wm = (wave >> 1) * 64, wn = (wave & 1) * 64;
  int lin = blockIdx.x + (blockIdx.y << 3);
  int idx = (lin & 7) * 64 + (lin >> 3);
  int tm = (idx >> 3) * 128, tn = (idx & 7) * 128;
  f32x4 acc[4][4] = {};
  for (int kt = 0; kt < K; kt += 64) {
#pragma unroll
    for (int it = 0; it < 4; ++it) {
      int gid = tid + it * 256;
      int row = gid >> 3, cb = gid & 7;
      gload16(Ab + (size_t)(tm + row) * K + kt + 8 * (cb ^ (row & 7)), &As[gid * 8]);
      gload16(Bt + (size_t)(tn + row) * K + kt + 8 * (cb ^ (row & 7)), &Bs[gid * 8]);
    }
    __syncthreads();
#pragma unroll
    for (int s = 0; s < 2; ++s) {
      bf16x8 af[4], bfr[4];
#pragma unroll
      for (int mf = 0; mf < 4; ++mf)
        af[mf] = *(const bf16x8*)&As[(wm + mf * 16 + q) * 64 + 8 * ((4 * s + g) ^ qx7)];
#pragma unroll
      for (int nf = 0; nf < 4; ++nf)
        bfr[nf] = *(const bf16x8*)&Bs[(wn + nf * 16 + q) * 64 + 8 * ((4 * s + g) ^ qx7)];
#pragma unroll
      for (int mf = 0; mf < 4; ++mf)
#pragma unroll
        for (int nf = 0; nf < 4; ++nf)
          acc[mf][nf] = __builtin_amdgcn_mfma_f32_16x16x32_bf16(af[mf], bfr[nf], acc[mf][nf], 0, 0, 0);
    }
    __syncthreads();
  }
#pragma unroll
  for (int mf = 0; mf < 4; ++mf)
#pragma unroll
    for (int nf = 0; nf < 4; ++nf)
#pragma unroll
      for (int r = 0; r < 4; ++r) {
        int row = tm + wm + mf * 16 + 4 * g + r;
        int col = tn + wn + nf * 16 + q;
        Cp[(size_t)row * EMB + col] = acc[mf][nf][r];
      }
}

// ---------------- flash attention (R3 structure + latency cuts) ----------------
// Q,K bf16 [b][l][h*64+d] (Q pre-scaled by 0.125*log2e); VT bf16 [b][h][dv][l]; out bf16.
// Block px handles q-chunks {px, 31-px} serially (balanced). No setprio.
// Softmax: acc seeded with -m (MFMA C-in) so common path needs no per-element subtract.
__global__ __launch_bounds__(256) void attn_kernel(
    const unsigned short* Qb, const unsigned short* Kb, const unsigned short* VTb,
    const int* pad, unsigned short* Ob) {
  __shared__ __align__(16) unsigned short Ks[2][64 * 64];   // [kv][d], src-XOR-swizzled
  __shared__ __align__(16) unsigned short Vs[2][64 * 64];   // [dv][kv], src-XOR-swizzled
  __shared__ __align__(16) unsigned short Ps[4][16 * 64];   // per-wave P, XOR-swizzled
  __shared__ unsigned long long pm[32];                     // per-tile pad ballot
  int tid = threadIdx.x;
  int lane = tid & 63, wave = tid >> 6;
  int q = lane & 15, g = lane >> 4;
  int qx7 = q & 7;
  // XCD-chunked swizzle: 16 blocks of one (b,h) share an XCD L2
  int lin = blockIdx.x;
  int idx = (lin & 7) * 128 + (lin >> 3);
  int b = idx >> 8, h = (idx >> 4) & 15, px = idx & 15;
  int cA = px, cB = 31 - px;

  // precompute pad ballots for all 32 kv tiles (wave w covers tiles 8w..8w+7)
#pragma unroll
  for (int i = 0; i < 8; ++i) {
    int t = wave * 8 + i;
    int pv = pad[b * SEQ + t * 64 + lane];
    unsigned long long msk = __ballot(pv != 0);
    if (lane == 0) pm[t] = msk;
  }

  // hoist Q loads for both halves
  int qgA = cA * 64 + wave * 16 + q;
  int qgB = cB * 64 + wave * 16 + q;
  const unsigned short* QrowA = Qb + ((size_t)(b * SEQ + qgA)) * EMB + h * 64;
  const unsigned short* QrowB = Qb + ((size_t)(b * SEQ + qgB)) * EMB + h * 64;
  bf16x8 qfh[2][2];
  qfh[0][0] = *(const bf16x8*)(QrowA + 8 * g);
  qfh[0][1] = *(const bf16x8*)(QrowA + 32 + 8 * g);
  qfh[1][0] = *(const bf16x8*)(QrowB + 8 * g);
  qfh[1][1] = *(const bf16x8*)(QrowB + 32 + 8 * g);

  int srow = tid >> 3, scb = tid & 7;
  int ssw = 8 * (scb ^ (srow & 7));
  const unsigned short* Kbase = Kb + (size_t)b * SEQ * EMB + (size_t)srow * EMB + h * 64 + ssw;
  const unsigned short* Vbase = VTb + (((size_t)(b * NH + h)) * 64 + srow) * SEQ + ssw;

#pragma unroll 1
  for (int half = 0; half < 2; ++half) {
    int c = half ? cB : cA;
    int qg = half ? qgB : qgA;
    bf16x8 qf0 = qfh[half][0], qf1 = qfh[half][1];
    f32x4 o[4] = {};
    float m_run = 0.f, l_run = 0.f;

    // prologue: stage tile 0 into buf 0
#pragma unroll
    for (int it = 0; it < 2; ++it) {
      gload16(Kbase + (size_t)(it * 32) * EMB, &Ks[0][(tid + it * 256) * 8]);
      gload16(Vbase + (size_t)(it * 32) * SEQ, &Vs[0][(tid + it * 256) * 8]);
    }
    __syncthreads();  // also publishes pm[] on half==0

#pragma unroll 1
    for (int t = 0; t <= c; ++t) {
      int kvt = t * 64;
      int cur = t & 1;
      if (t < c) {
#pragma unroll
        for (int it = 0; it < 2; ++it) {
          gload16(Kbase + (size_t)(kvt + 64 + it * 32) * EMB, &Ks[cur ^ 1][(tid + it * 256) * 8]);
          gload16(Vbase + (size_t)(kvt + 64) + (size_t)(it * 32) * SEQ, &Vs[cur ^ 1][(tid + it * 256) * 8]);
        }
      }
      unsigned long long pmask = pm[t];
      bool notfull = (pmask != ~0ull);

      // QK: S^T[kv][q] seeded with -m_run (additive C-in)
      f32x4 sf[4];
      f32x4 seed = {-m_run, -m_run, -m_run, -m_run};
#pragma unroll
      for (int mf = 0; mf < 4; ++mf) sf[mf] = seed;
#pragma unroll
      for (int s = 0; s < 2; ++s) {
#pragma unroll
        for (int mf = 0; mf < 4; ++mf) {
          bf16x8 kf = *(const bf16x8*)&Ks[cur][(mf * 16 + q) * 64 + 8 * ((4 * s + g) ^ qx7)];
          sf[mf] = __builtin_amdgcn_mfma_f32_16x16x32_bf16(kf, s ? qf1 : qf0, sf[mf], 0, 0, 0);
        }
      }

      // mask (rare path)
      if (t == c || notfull) {
#pragma unroll
        for (int mf = 0; mf < 4; ++mf)
#pragma unroll
          for (int r = 0; r < 4; ++r) {
            int kvl = mf * 16 + 4 * g + r;
            bool keep = (kvt + kvl <= qg) && ((pmask >> kvl) & 1ULL);
            sf[mf][r] = keep ? sf[mf][r] : -INFINITY;
          }
      }

      // balanced max tree over 16 lane-local values, then 2 shuffles
      float t0 = fmaxf(fmaxf(sf[0][0], sf[0][1]), fmaxf(sf[0][2], sf[0][3]));
      float t1 = fmaxf(fmaxf(sf[1][0], sf[1][1]), fmaxf(sf[1][2], sf[1][3]));
      float t2 = fmaxf(fmaxf(sf[2][0], sf[2][1]), fmaxf(sf[2][2], sf[2][3]));
      float t3 = fmaxf(fmaxf(sf[3][0], sf[3][1]), fmaxf(sf[3][2], sf[3][3]));
      float tmax = fmaxf(fmaxf(t0, t1), fmaxf(t2, t3));
      tmax = fmaxf(tmax, __shfl_xor(tmax, 16));
      tmax = fmaxf(tmax, __shfl_xor(tmax, 32));

      // defer-max: values already shifted by -m_run; rescale only if growth > 8
      if (!__all(tmax <= 8.0f)) {
        float d = fmaxf(tmax, 0.f);
        float alpha = __builtin_amdgcn_exp2f(-d);
        l_run *= alpha;
#pragma unroll
        for (int mv = 0; mv < 4; ++mv) o[mv] *= alpha;
#pragma unroll
        for (int mf = 0; mf < 4; ++mf)
#pragma unroll
          for (int r = 0; r < 4; ++r) sf[mf][r] -= d;
        m_run += d;
      }

      // exp2 (no subtract in common path) + rsum + pack
      float rsum = 0.f;
      float pvv[16];
#pragma unroll
      for (int mf = 0; mf < 4; ++mf)
#pragma unroll
        for (int r = 0; r < 4; ++r) {
          float p = __builtin_amdgcn_exp2f(sf[mf][r]);
          pvv[mf * 4 + r] = p;
          rsum += p;
        }
#pragma unroll
      for (int mf = 0; mf < 4; ++mf) {
        uint2 w;
        w.x = cvtpk(pvv[mf * 4 + 0], pvv[mf * 4 + 1]);
        w.y = cvtpk(pvv[mf * 4 + 2], pvv[mf * 4 + 3]);
        int cbP = 2 * mf + (g >> 1);
        *(uint2*)&Ps[wave][q * 64 + 8 * (cbP ^ qx7) + 4 * (g & 1)] = w;
      }
      rsum += __shfl_xor(rsum, 16);
      rsum += __shfl_xor(rsum, 32);
      l_run += rsum;

      // PV: O^T[dv][q] += V^T[dv][kv] * P^T[kv][q]
#pragma unroll
      for (int s = 0; s < 2; ++s) {
        bf16x8 pb = *(const bf16x8*)&Ps[wave][q * 64 + 8 * ((4 * s + g) ^ qx7)];
#pragma unroll
        for (int mv = 0; mv < 4; ++mv) {
          bf16x8 va = *(const bf16x8*)&Vs[cur][(mv * 16 + q) * 64 + 8 * ((4 * s + g) ^ qx7)];
          o[mv] = __builtin_amdgcn_mfma_f32_16x16x32_bf16(va, pb, o[mv], 0, 0, 0);
        }
      }
      __syncthreads();  // publishes next buf, protects cur for overwrite at t+2
    }

    float inv = 1.0f / l_run;
    unsigned short* Orow = Ob + ((size_t)(b * SEQ + qg)) * EMB + h * 64;
#pragma unroll
    for (int mv = 0; mv < 4; ++mv) {
      uint2 w;
      w.x = cvtpk(o[mv][0] * inv, o[mv][1] * inv);
      w.y = cvtpk(o[mv][2] * inv, o[mv][3] * inv);
      *(uint2*)&Orow[mv * 16 + 4 * g] = w;
    }
  }
}

extern "C" void kernel_launch(void* const* d_in, const int* in_sizes, int n_in,
                              void* d_out, int out_size, void* d_ws, size_t ws_size,
                              hipStream_t stream) {
  const float* query = (const float*)d_in[0];
  const float* key   = (const float*)d_in[1];
  const float* value = (const float*)d_in[2];
  const int*   pad   = (const int*)d_in[3];
  const float* Wq = (const float*)d_in[4];
  const float* Wk = (const float*)d_in[5];
  const float* Wv = (const float*)d_in[6];
  const float* Wo = (const float*)d_in[7];

  unsigned short* WqT = (unsigned short*)d_ws;
  unsigned short* WkT = WqT + (size_t)EMB * EMB;
  unsigned short* WvT = WkT + (size_t)EMB * EMB;
  unsigned short* WoT = WvT + (size_t)EMB * EMB;
  unsigned short* Qb  = WoT + (size_t)EMB * EMB;
  unsigned short* Kb  = Qb + (size_t)MROWS * EMB;
  unsigned short* VTb = Kb + (size_t)MROWS * EMB;
  unsigned short* Ab  = VTb + (size_t)MROWS * EMB;

  wtrans_kernel<<<dim3(EMB / 32, EMB / 32, 4), dim3(32, 8), 0, stream>>>(
      Wq, Wk, Wv, Wo, WqT, WkT, WvT, WoT);
  qkv_gemm<<<dim3(8, 64, 3), 256, 0, stream>>>(query, key, value, WqT, WkT, WvT, Qb, Kb, VTb);
  attn_kernel<<<dim3(1024), 256, 0, stream>>>(Qb, Kb, VTb, pad, Ab);
  out_gemm<<<dim3(8, 64), 256, 0, stream>>>(Ab, WoT, (float*)d_out);
}

// Round 7
// 207.136 us; speedup vs baseline: 1.1738x; 1.0609x over previous
//
#include <hip/hip_runtime.h>
#include <hip/hip_bf16.h>

typedef short bf16x8 __attribute__((ext_vector_type(8)));
typedef float f32x4 __attribute__((ext_vector_type(4)));

#define EMB 1024
#define NH 16
#define SEQ 2048
#define BATCH 4
#define MROWS (BATCH * SEQ)

static __device__ inline unsigned short f2bf(float f) {
  unsigned u = __float_as_uint(f);
  u += 0x7fffu + ((u >> 16) & 1u);
  return (unsigned short)(u >> 16);
}

static __device__ inline unsigned cvtpk(float lo, float hi) {
  unsigned r;
  asm("v_cvt_pk_bf16_f32 %0, %1, %2" : "=v"(r) : "v"(lo), "v"(hi));
  return r;
}

static __device__ inline void gload16(const void* g, void* l) {
  __builtin_amdgcn_global_load_lds(
      (const __attribute__((address_space(1))) unsigned int*)g,
      (__attribute__((address_space(3))) unsigned int*)l, 16, 0, 0);
}

// ---------------- weight transpose + cast: W[k][n] f32 -> WT[n][k] bf16 ----------------
// z==0 (Wq) additionally folds in 0.125*log2(e) so attention logits are in exp2 domain.
__global__ __launch_bounds__(256) void wtrans_kernel(
    const float* w0, const float* w1, const float* w2, const float* w3,
    unsigned short* o0, unsigned short* o1, unsigned short* o2, unsigned short* o3) {
  __shared__ float t[32][33];
  int z = blockIdx.z;
  const float* W = z == 0 ? w0 : z == 1 ? w1 : z == 2 ? w2 : w3;
  unsigned short* O = z == 0 ? o0 : z == 1 ? o1 : z == 2 ? o2 : o3;
  float sc = (z == 0) ? 0.18033688011112042f : 1.0f;
  int bx = blockIdx.x * 32;  // k block
  int by = blockIdx.y * 32;  // n block
  int tx = threadIdx.x, ty = threadIdx.y;  // (32,8)
#pragma unroll
  for (int j = 0; j < 4; ++j)
    t[ty + j * 8][tx] = W[(size_t)(bx + ty + j * 8) * EMB + by + tx];
  __syncthreads();
#pragma unroll
  for (int j = 0; j < 4; ++j)
    O[(size_t)(by + ty + j * 8) * EMB + bx + tx] = f2bf(t[tx][ty + j * 8] * sc);
}

// ---------------- GEMM: C[M=8192][N=1024] = A[M][K=1024] * BT[N][K]^T ----------------
// IN_F32: 1 = A is f32 (cast to bf16 while staging), 0 = A is bf16 (global_load_lds)
// OUT_MODE: 0 = bf16 normal [m][n], 1 = bf16 V-transposed [b][h][dv][l], 2 = f32 [m][n]
template <int IN_F32, int OUT_MODE>
__global__ __launch_bounds__(256) void gemm_kernel(const void* Ap, const unsigned short* Bt, void* Cp) {
  __shared__ __align__(16) unsigned short As[128 * 64];  // XOR-swizzled cols
  __shared__ __align__(16) unsigned short Bs[128 * 64];
  const int K = EMB;
  int tid = threadIdx.x;
  int lane = tid & 63, wave = tid >> 6;
  int q = lane & 15, g = lane >> 4;
  int qx7 = q & 7;
  int wm = (wave >> 1) * 64, wn = (wave & 1) * 64;
  int lin = blockIdx.x + (blockIdx.y << 3);
  int idx = (lin & 7) * 64 + (lin >> 3);
  int tm = (idx >> 3) * 128, tn = (idx & 7) * 128;
  f32x4 acc[4][4] = {};
  for (int kt = 0; kt < K; kt += 64) {
    if (IN_F32) {
      const float* A = (const float*)Ap;
#pragma unroll
      for (int it = 0; it < 4; ++it) {
        int gid = tid + it * 256;
        int row = gid >> 3, cb = gid & 7;
        const float4* s0 = (const float4*)(A + (size_t)(tm + row) * K + kt + cb * 8);
        float4 x = s0[0], y = s0[1];
        uint4 w;
        w.x = cvtpk(x.x, x.y); w.y = cvtpk(x.z, x.w);
        w.z = cvtpk(y.x, y.y); w.w = cvtpk(y.z, y.w);
        *(uint4*)&As[row * 64 + 8 * (cb ^ (row & 7))] = w;
      }
    } else {
      const unsigned short* A = (const unsigned short*)Ap;
#pragma unroll
      for (int it = 0; it < 4; ++it) {
        int gid = tid + it * 256;
        int row = gid >> 3, cb = gid & 7;
        gload16(A + (size_t)(tm + row) * K + kt + 8 * (cb ^ (row & 7)), &As[gid * 8]);
      }
    }
#pragma unroll
    for (int it = 0; it < 4; ++it) {
      int gid = tid + it * 256;
      int row = gid >> 3, cb = gid & 7;
      gload16(Bt + (size_t)(tn + row) * K + kt + 8 * (cb ^ (row & 7)), &Bs[gid * 8]);
    }
    __syncthreads();
#pragma unroll
    for (int s = 0; s < 2; ++s) {
      bf16x8 af[4], bfr[4];
#pragma unroll
      for (int mf = 0; mf < 4; ++mf)
        af[mf] = *(const bf16x8*)&As[(wm + mf * 16 + q) * 64 + 8 * ((4 * s + g) ^ qx7)];
#pragma unroll
      for (int nf = 0; nf < 4; ++nf)
        bfr[nf] = *(const bf16x8*)&Bs[(wn + nf * 16 + q) * 64 + 8 * ((4 * s + g) ^ qx7)];
#pragma unroll
      for (int mf = 0; mf < 4; ++mf)
#pragma unroll
        for (int nf = 0; nf < 4; ++nf)
          acc[mf][nf] = __builtin_amdgcn_mfma_f32_16x16x32_bf16(af[mf], bfr[nf], acc[mf][nf], 0, 0, 0);
    }
    __syncthreads();
  }
  if (OUT_MODE == 0) {
    unsigned short* C = (unsigned short*)Cp;
#pragma unroll
    for (int mf = 0; mf < 4; ++mf)
#pragma unroll
      for (int nf = 0; nf < 4; ++nf)
#pragma unroll
        for (int r = 0; r < 4; ++r) {
          int row = tm + wm + mf * 16 + 4 * g + r;
          int col = tn + wn + nf * 16 + q;
          C[(size_t)row * EMB + col] = f2bf(acc[mf][nf][r]);
        }
  } else if (OUT_MODE == 1) {
    unsigned short* C = (unsigned short*)Cp;
#pragma unroll
    for (int mf = 0; mf < 4; ++mf) {
      int m0 = tm + wm + mf * 16 + 4 * g;
      int b = m0 >> 11, l = m0 & 2047;
#pragma unroll
      for (int nf = 0; nf < 4; ++nf) {
        int n = tn + wn + nf * 16 + q;
        int h = n >> 6, dv = n & 63;
        uint2 w;
        w.x = cvtpk(acc[mf][nf][0], acc[mf][nf][1]);
        w.y = cvtpk(acc[mf][nf][2], acc[mf][nf][3]);
        *(uint2*)&C[(((size_t)b * NH + h) * 64 + dv) * SEQ + l] = w;
      }
    }
  } else {
    float* C = (float*)Cp;
#pragma unroll
    for (int mf = 0; mf < 4; ++mf)
#pragma unroll
      for (int nf = 0; nf < 4; ++nf)
#pragma unroll
        for (int r = 0; r < 4; ++r) {
          int row = tm + wm + mf * 16 + 4 * g + r;
          int col = tn + wn + nf * 16 + q;
          C[(size_t)row * EMB + col] = acc[mf][nf][r];
        }
  }
}

// ---------------- flash attention: R3 structure + setprio + allvalid-SGPR + 4 blocks/CU ----------------
// Q,K bf16 [b][l][h*64+d] (Q pre-scaled by 0.125*log2e); VT bf16 [b][h][dv][l]; out bf16.
// Block px handles q-chunks {px, 31-px} serially (balanced).
// LDS = exactly 40960 B -> 4 blocks/CU (160 KiB exact).
__global__ __launch_bounds__(256) void attn_kernel(
    const unsigned short* Qb, const unsigned short* Kb, const unsigned short* VTb,
    const int* pad, unsigned short* Ob) {
  __shared__ __align__(16) unsigned short Ks[2][64 * 64];   // 16 KB, [kv][d] src-XOR-swizzled
  __shared__ __align__(16) unsigned short Vs[2][64 * 64];   // 16 KB, [dv][kv] src-XOR-swizzled
  __shared__ __align__(16) unsigned short Ps[4][16 * 64];   // 8 KB, per-wave P, XOR-swizzled
  int tid = threadIdx.x;
  int lane = tid & 63, wave = tid >> 6;
  int q = lane & 15, g = lane >> 4;
  int qx7 = q & 7;
  // XCD-chunked swizzle: 16 blocks of one (b,h) share an XCD L2
  int lin = blockIdx.x;
  int idx = (lin & 7) * 128 + (lin >> 3);
  int b = idx >> 8, h = (idx >> 4) & 15, px = idx & 15;
  int cA = px, cB = 31 - px;

  // per-tile "fully valid" bitmask, wave-uniform (no LDS). Rare non-full tiles re-ballot inline.
  unsigned allvalid = 0;
#pragma unroll 8
  for (int t0 = 0; t0 < 32; ++t0) {
    int pv = pad[b * SEQ + t0 * 64 + lane];
    if (__ballot(pv != 0) == ~0ull) allvalid |= (1u << t0);
  }

  // hoist Q loads for both halves (named regs, no runtime-indexed array)
  int qgA = cA * 64 + wave * 16 + q;
  int qgB = cB * 64 + wave * 16 + q;
  const unsigned short* QrowA = Qb + ((size_t)(b * SEQ + qgA)) * EMB + h * 64;
  const unsigned short* QrowB = Qb + ((size_t)(b * SEQ + qgB)) * EMB + h * 64;
  bf16x8 qfA0 = *(const bf16x8*)(QrowA + 8 * g);
  bf16x8 qfA1 = *(const bf16x8*)(QrowA + 32 + 8 * g);
  bf16x8 qfB0 = *(const bf16x8*)(QrowB + 8 * g);
  bf16x8 qfB1 = *(const bf16x8*)(QrowB + 32 + 8 * g);

  int srow = tid >> 3, scb = tid & 7;
  int ssw = 8 * (scb ^ (srow & 7));
  const unsigned short* Kbase = Kb + (size_t)b * SEQ * EMB + (size_t)srow * EMB + h * 64 + ssw;
  const unsigned short* Vbase = VTb + (((size_t)(b * NH + h)) * 64 + srow) * SEQ + ssw;

#pragma unroll 1
  for (int half = 0; half < 2; ++half) {
    int c = half ? cB : cA;
    int qg = half ? qgB : qgA;
    bf16x8 qf0 = half ? qfB0 : qfA0;
    bf16x8 qf1 = half ? qfB1 : qfA1;
    f32x4 o[4] = {};
    float m_run = 0.f, l_run = 0.f;

    // prologue: stage tile 0 into buf 0
#pragma unroll
    for (int it = 0; it < 2; ++it) {
      gload16(Kbase + (size_t)(it * 32) * EMB, &Ks[0][(tid + it * 256) * 8]);
      gload16(Vbase + (size_t)(it * 32) * SEQ, &Vs[0][(tid + it * 256) * 8]);
    }
    __syncthreads();

#pragma unroll 1
    for (int t = 0; t <= c; ++t) {
      int kvt = t * 64;
      int cur = t & 1;
      if (t < c) {
#pragma unroll
        for (int it = 0; it < 2; ++it) {
          gload16(Kbase + (size_t)(kvt + 64 + it * 32) * EMB, &Ks[cur ^ 1][(tid + it * 256) * 8]);
          gload16(Vbase + (size_t)(kvt + 64) + (size_t)(it * 32) * SEQ, &Vs[cur ^ 1][(tid + it * 256) * 8]);
        }
      }
      bool tilefull = (allvalid >> t) & 1;

      // QK: S^T[kv][q] seeded with -m_run (additive C-in)
      f32x4 sf[4];
      f32x4 seed = {-m_run, -m_run, -m_run, -m_run};
#pragma unroll
      for (int mf = 0; mf < 4; ++mf) sf[mf] = seed;
      __builtin_amdgcn_s_setprio(1);
#pragma unroll
      for (int s = 0; s < 2; ++s) {
#pragma unroll
        for (int mf = 0; mf < 4; ++mf) {
          bf16x8 kf = *(const bf16x8*)&Ks[cur][(mf * 16 + q) * 64 + 8 * ((4 * s + g) ^ qx7)];
          sf[mf] = __builtin_amdgcn_mfma_f32_16x16x32_bf16(kf, s ? qf1 : qf0, sf[mf], 0, 0, 0);
        }
      }
      __builtin_amdgcn_s_setprio(0);

      // mask (rare path: diagonal tile or padded tile)
      if (t == c || !tilefull) {
        unsigned long long pmask =
            tilefull ? ~0ull : __ballot(pad[b * SEQ + kvt + lane] != 0);
#pragma unroll
        for (int mf = 0; mf < 4; ++mf)
#pragma unroll
          for (int r = 0; r < 4; ++r) {
            int kvl = mf * 16 + 4 * g + r;
            bool keep = (kvt + kvl <= qg) && ((pmask >> kvl) & 1ULL);
            sf[mf][r] = keep ? sf[mf][r] : -INFINITY;
          }
      }

      // balanced max tree over 16 lane-local values, then 2 shuffles
      float t0 = fmaxf(fmaxf(sf[0][0], sf[0][1]), fmaxf(sf[0][2], sf[0][3]));
      float t1 = fmaxf(fmaxf(sf[1][0], sf[1][1]), fmaxf(sf[1][2], sf[1][3]));
      float t2 = fmaxf(fmaxf(sf[2][0], sf[2][1]), fmaxf(sf[2][2], sf[2][3]));
      float t3 = fmaxf(fmaxf(sf[3][0], sf[3][1]), fmaxf(sf[3][2], sf[3][3]));
      float tmax = fmaxf(fmaxf(t0, t1), fmaxf(t2, t3));
      tmax = fmaxf(tmax, __shfl_xor(tmax, 16));
      tmax = fmaxf(tmax, __shfl_xor(tmax, 32));

      // defer-max: values already shifted by -m_run; rescale only if growth > 8
      if (!__all(tmax <= 8.0f)) {
        float d = fmaxf(tmax, 0.f);
        float alpha = __builtin_amdgcn_exp2f(-d);
        l_run *= alpha;
#pragma unroll
        for (int mv = 0; mv < 4; ++mv) o[mv] *= alpha;
#pragma unroll
        for (int mf = 0; mf < 4; ++mf)
#pragma unroll
          for (int r = 0; r < 4; ++r) sf[mf][r] -= d;
        m_run += d;
      }

      // exp2 (no subtract in common path) + rsum + pack
      float rsum = 0.f;
      float pvv[16];
#pragma unroll
      for (int mf = 0; mf < 4; ++mf)
#pragma unroll
        for (int r = 0; r < 4; ++r) {
          float p = __builtin_amdgcn_exp2f(sf[mf][r]);
          pvv[mf * 4 + r] = p;
          rsum += p;
        }
#pragma unroll
      for (int mf = 0; mf < 4; ++mf) {
        uint2 w;
        w.x = cvtpk(pvv[mf * 4 + 0], pvv[mf * 4 + 1]);
        w.y = cvtpk(pvv[mf * 4 + 2], pvv[mf * 4 + 3]);
        int cbP = 2 * mf + (g >> 1);
        *(uint2*)&Ps[wave][q * 64 + 8 * (cbP ^ qx7) + 4 * (g & 1)] = w;
      }
      rsum += __shfl_xor(rsum, 16);
      rsum += __shfl_xor(rsum, 32);
      l_run += rsum;

      // PV: O^T[dv][q] += V^T[dv][kv] * P^T[kv][q]
      __builtin_amdgcn_s_setprio(1);
#pragma unroll
      for (int s = 0; s < 2; ++s) {
        bf16x8 pb = *(const bf16x8*)&Ps[wave][q * 64 + 8 * ((4 * s + g) ^ qx7)];
#pragma unroll
        for (int mv = 0; mv < 4; ++mv) {
          bf16x8 va = *(const bf16x8*)&Vs[cur][(mv * 16 + q) * 64 + 8 * ((4 * s + g) ^ qx7)];
          o[mv] = __builtin_amdgcn_mfma_f32_16x16x32_bf16(va, pb, o[mv], 0, 0, 0);
        }
      }
      __builtin_amdgcn_s_setprio(0);
      __syncthreads();  // publishes next buf, protects cur for overwrite at t+2
    }

    float inv = 1.0f / l_run;
    unsigned short* Orow = Ob + ((size_t)(b * SEQ + qg)) * EMB + h * 64;
#pragma unroll
    for (int mv = 0; mv < 4; ++mv) {
      uint2 w;
      w.x = cvtpk(o[mv][0] * inv, o[mv][1] * inv);
      w.y = cvtpk(o[mv][2] * inv, o[mv][3] * inv);
      *(uint2*)&Orow[mv * 16 + 4 * g] = w;
    }
  }
}

extern "C" void kernel_launch(void* const* d_in, const int* in_sizes, int n_in,
                              void* d_out, int out_size, void* d_ws, size_t ws_size,
                              hipStream_t stream) {
  const float* query = (const float*)d_in[0];
  const float* key   = (const float*)d_in[1];
  const float* value = (const float*)d_in[2];
  const int*   pad   = (const int*)d_in[3];
  const float* Wq = (const float*)d_in[4];
  const float* Wk = (const float*)d_in[5];
  const float* Wv = (const float*)d_in[6];
  const float* Wo = (const float*)d_in[7];

  unsigned short* WqT = (unsigned short*)d_ws;
  unsigned short* WkT = WqT + (size_t)EMB * EMB;
  unsigned short* WvT = WkT + (size_t)EMB * EMB;
  unsigned short* WoT = WvT + (size_t)EMB * EMB;
  unsigned short* Qb  = WoT + (size_t)EMB * EMB;
  unsigned short* Kb  = Qb + (size_t)MROWS * EMB;
  unsigned short* VTb = Kb + (size_t)MROWS * EMB;
  unsigned short* Ab  = VTb + (size_t)MROWS * EMB;

  wtrans_kernel<<<dim3(EMB / 32, EMB / 32, 4), dim3(32, 8), 0, stream>>>(
      Wq, Wk, Wv, Wo, WqT, WkT, WvT, WoT);
  gemm_kernel<1, 0><<<dim3(8, 64), 256, 0, stream>>>(query, WqT, Qb);
  gemm_kernel<1, 0><<<dim3(8, 64), 256, 0, stream>>>(key, WkT, Kb);
  gemm_kernel<1, 1><<<dim3(8, 64), 256, 0, stream>>>(value, WvT, VTb);
  attn_kernel<<<dim3(1024), 256, 0, stream>>>(Qb, Kb, VTb, pad, Ab);
  gemm_kernel<0, 2><<<dim3(8, 64), 256, 0, stream>>>(Ab, WoT, (float*)d_out);
}

// Round 8
// 202.257 us; speedup vs baseline: 1.2022x; 1.0241x over previous
//
#include <hip/hip_runtime.h>
#include <hip/hip_bf16.h>

typedef short bf16x8 __attribute__((ext_vector_type(8)));
typedef float f32x4 __attribute__((ext_vector_type(4)));

#define EMB 1024
#define NH 16
#define SEQ 2048
#define BATCH 4
#define MROWS (BATCH * SEQ)

static __device__ inline unsigned short f2bf(float f) {
  unsigned u = __float_as_uint(f);
  u += 0x7fffu + ((u >> 16) & 1u);
  return (unsigned short)(u >> 16);
}

static __device__ inline unsigned cvtpk(float lo, float hi) {
  unsigned r;
  asm("v_cvt_pk_bf16_f32 %0, %1, %2" : "=v"(r) : "v"(lo), "v"(hi));
  return r;
}

static __device__ inline void gload16(const void* g, void* l) {
  __builtin_amdgcn_global_load_lds(
      (const __attribute__((address_space(1))) unsigned int*)g,
      (__attribute__((address_space(3))) unsigned int*)l, 16, 0, 0);
}

// ---------------- weight transpose + cast: W[k][n] f32 -> WT[n][k] bf16 ----------------
// z==0 (Wq) additionally folds in 0.125*log2(e) so attention logits are in exp2 domain.
__global__ __launch_bounds__(256) void wtrans_kernel(
    const float* w0, const float* w1, const float* w2, const float* w3,
    unsigned short* o0, unsigned short* o1, unsigned short* o2, unsigned short* o3) {
  __shared__ float t[32][33];
  int z = blockIdx.z;
  const float* W = z == 0 ? w0 : z == 1 ? w1 : z == 2 ? w2 : w3;
  unsigned short* O = z == 0 ? o0 : z == 1 ? o1 : z == 2 ? o2 : o3;
  float sc = (z == 0) ? 0.18033688011112042f : 1.0f;
  int bx = blockIdx.x * 32;  // k block
  int by = blockIdx.y * 32;  // n block
  int tx = threadIdx.x, ty = threadIdx.y;  // (32,8)
#pragma unroll
  for (int j = 0; j < 4; ++j)
    t[ty + j * 8][tx] = W[(size_t)(bx + ty + j * 8) * EMB + by + tx];
  __syncthreads();
#pragma unroll
  for (int j = 0; j < 4; ++j)
    O[(size_t)(by + ty + j * 8) * EMB + bx + tx] = f2bf(t[tx][ty + j * 8] * sc);
}

// ---------------- GEMM: C[M=8192][N=1024] = A[M][K=1024] * BT[N][K]^T ----------------
// IN_F32: 1 = A is f32 (cast to bf16 while staging), 0 = A is bf16 (global_load_lds)
// OUT_MODE: 0 = bf16 normal [m][n], 1 = bf16 V-transposed [b][h][dv][l], 2 = f32 [m][n]
template <int IN_F32, int OUT_MODE>
__global__ __launch_bounds__(256) void gemm_kernel(const void* Ap, const unsigned short* Bt, void* Cp) {
  __shared__ __align__(16) unsigned short As[128 * 64];  // XOR-swizzled cols
  __shared__ __align__(16) unsigned short Bs[128 * 64];
  const int K = EMB;
  int tid = threadIdx.x;
  int lane = tid & 63, wave = tid >> 6;
  int q = lane & 15, g = lane >> 4;
  int qx7 = q & 7;
  int wm = (wave >> 1) * 64, wn = (wave & 1) * 64;
  int lin = blockIdx.x + (blockIdx.y << 3);
  int idx = (lin & 7) * 64 + (lin >> 3);
  int tm = (idx >> 3) * 128, tn = (idx & 7) * 128;
  f32x4 acc[4][4] = {};
  for (int kt = 0; kt < K; kt += 64) {
    if (IN_F32) {
      const float* A = (const float*)Ap;
#pragma unroll
      for (int it = 0; it < 4; ++it) {
        int gid = tid + it * 256;
        int row = gid >> 3, cb = gid & 7;
        const float4* s0 = (const float4*)(A + (size_t)(tm + row) * K + kt + cb * 8);
        float4 x = s0[0], y = s0[1];
        uint4 w;
        w.x = cvtpk(x.x, x.y); w.y = cvtpk(x.z, x.w);
        w.z = cvtpk(y.x, y.y); w.w = cvtpk(y.z, y.w);
        *(uint4*)&As[row * 64 + 8 * (cb ^ (row & 7))] = w;
      }
    } else {
      const unsigned short* A = (const unsigned short*)Ap;
#pragma unroll
      for (int it = 0; it < 4; ++it) {
        int gid = tid + it * 256;
        int row = gid >> 3, cb = gid & 7;
        gload16(A + (size_t)(tm + row) * K + kt + 8 * (cb ^ (row & 7)), &As[gid * 8]);
      }
    }
#pragma unroll
    for (int it = 0; it < 4; ++it) {
      int gid = tid + it * 256;
      int row = gid >> 3, cb = gid & 7;
      gload16(Bt + (size_t)(tn + row) * K + kt + 8 * (cb ^ (row & 7)), &Bs[gid * 8]);
    }
    __syncthreads();
#pragma unroll
    for (int s = 0; s < 2; ++s) {
      bf16x8 af[4], bfr[4];
#pragma unroll
      for (int mf = 0; mf < 4; ++mf)
        af[mf] = *(const bf16x8*)&As[(wm + mf * 16 + q) * 64 + 8 * ((4 * s + g) ^ qx7)];
#pragma unroll
      for (int nf = 0; nf < 4; ++nf)
        bfr[nf] = *(const bf16x8*)&Bs[(wn + nf * 16 + q) * 64 + 8 * ((4 * s + g) ^ qx7)];
#pragma unroll
      for (int mf = 0; mf < 4; ++mf)
#pragma unroll
        for (int nf = 0; nf < 4; ++nf)
          acc[mf][nf] = __builtin_amdgcn_mfma_f32_16x16x32_bf16(af[mf], bfr[nf], acc[mf][nf], 0, 0, 0);
    }
    __syncthreads();
  }
  if (OUT_MODE == 0) {
    unsigned short* C = (unsigned short*)Cp;
#pragma unroll
    for (int mf = 0; mf < 4; ++mf)
#pragma unroll
      for (int nf = 0; nf < 4; ++nf)
#pragma unroll
        for (int r = 0; r < 4; ++r) {
          int row = tm + wm + mf * 16 + 4 * g + r;
          int col = tn + wn + nf * 16 + q;
          C[(size_t)row * EMB + col] = f2bf(acc[mf][nf][r]);
        }
  } else if (OUT_MODE == 1) {
    unsigned short* C = (unsigned short*)Cp;
#pragma unroll
    for (int mf = 0; mf < 4; ++mf) {
      int m0 = tm + wm + mf * 16 + 4 * g;
      int b = m0 >> 11, l = m0 & 2047;
#pragma unroll
      for (int nf = 0; nf < 4; ++nf) {
        int n = tn + wn + nf * 16 + q;
        int h = n >> 6, dv = n & 63;
        uint2 w;
        w.x = cvtpk(acc[mf][nf][0], acc[mf][nf][1]);
        w.y = cvtpk(acc[mf][nf][2], acc[mf][nf][3]);
        *(uint2*)&C[(((size_t)b * NH + h) * 64 + dv) * SEQ + l] = w;
      }
    }
  } else {
    float* C = (float*)Cp;
#pragma unroll
    for (int mf = 0; mf < 4; ++mf)
#pragma unroll
      for (int nf = 0; nf < 4; ++nf)
#pragma unroll
        for (int r = 0; r < 4; ++r) {
          int row = tm + wm + mf * 16 + 4 * g + r;
          int col = tn + wn + nf * 16 + q;
          C[(size_t)row * EMB + col] = acc[mf][nf][r];
        }
  }
}

// ---------------- flash attention: short-chain softmax ----------------
// Q,K bf16 [b][l][h*64+d] (Q pre-scaled by 0.125*log2e); VT bf16 [b][h][dv][l]; out bf16.
// Block px handles q-chunks {px, 31-px} serially (balanced). LDS 40960 B.
// Critical-path cuts: (1) __all on lane-local max (shuffles only in rare rescale path),
// (2) optimistic exp2 concurrent with the max tree, (3) l accumulated via mfma(ones, P).
__global__ __launch_bounds__(256) void attn_kernel(
    const unsigned short* Qb, const unsigned short* Kb, const unsigned short* VTb,
    const int* pad, unsigned short* Ob) {
  __shared__ __align__(16) unsigned short Ks[2][64 * 64];   // 16 KB, [kv][d] src-XOR-swizzled
  __shared__ __align__(16) unsigned short Vs[2][64 * 64];   // 16 KB, [dv][kv] src-XOR-swizzled
  __shared__ __align__(16) unsigned short Ps[4][16 * 64];   // 8 KB, per-wave P, XOR-swizzled
  int tid = threadIdx.x;
  int lane = tid & 63, wave = tid >> 6;
  int q = lane & 15, g = lane >> 4;
  int qx7 = q & 7;
  // XCD-chunked swizzle: 16 blocks of one (b,h) share an XCD L2
  int lin = blockIdx.x;
  int idx = (lin & 7) * 128 + (lin >> 3);
  int b = idx >> 8, h = (idx >> 4) & 15, px = idx & 15;
  int cA = px, cB = 31 - px;

  // per-tile "fully valid" bitmask, wave-uniform (no LDS). Rare non-full tiles re-ballot inline.
  unsigned allvalid = 0;
#pragma unroll 8
  for (int t0 = 0; t0 < 32; ++t0) {
    int pv = pad[b * SEQ + t0 * 64 + lane];
    if (__ballot(pv != 0) == ~0ull) allvalid |= (1u << t0);
  }

  // hoist Q loads for both halves (named regs, no runtime-indexed array)
  int qgA = cA * 64 + wave * 16 + q;
  int qgB = cB * 64 + wave * 16 + q;
  const unsigned short* QrowA = Qb + ((size_t)(b * SEQ + qgA)) * EMB + h * 64;
  const unsigned short* QrowB = Qb + ((size_t)(b * SEQ + qgB)) * EMB + h * 64;
  bf16x8 qfA0 = *(const bf16x8*)(QrowA + 8 * g);
  bf16x8 qfA1 = *(const bf16x8*)(QrowA + 32 + 8 * g);
  bf16x8 qfB0 = *(const bf16x8*)(QrowB + 8 * g);
  bf16x8 qfB1 = *(const bf16x8*)(QrowB + 32 + 8 * g);

  bf16x8 ones;
#pragma unroll
  for (int i = 0; i < 8; ++i) ones[i] = (short)0x3F80;  // bf16 1.0

  int srow = tid >> 3, scb = tid & 7;
  int ssw = 8 * (scb ^ (srow & 7));
  const unsigned short* Kbase = Kb + (size_t)b * SEQ * EMB + (size_t)srow * EMB + h * 64 + ssw;
  const unsigned short* Vbase = VTb + (((size_t)(b * NH + h)) * 64 + srow) * SEQ + ssw;

#pragma unroll 1
  for (int half = 0; half < 2; ++half) {
    int c = half ? cB : cA;
    int qg = half ? qgB : qgA;
    bf16x8 qf0 = half ? qfB0 : qfA0;
    bf16x8 qf1 = half ? qfB1 : qfA1;
    f32x4 o[4] = {};
    f32x4 ol = {};           // ol[0] = running softmax denominator (column sum of P)
    float m_run = 0.f;

    // prologue: stage tile 0 into buf 0
#pragma unroll
    for (int it = 0; it < 2; ++it) {
      gload16(Kbase + (size_t)(it * 32) * EMB, &Ks[0][(tid + it * 256) * 8]);
      gload16(Vbase + (size_t)(it * 32) * SEQ, &Vs[0][(tid + it * 256) * 8]);
    }
    __syncthreads();

#pragma unroll 1
    for (int t = 0; t <= c; ++t) {
      int kvt = t * 64;
      int cur = t & 1;
      if (t < c) {
#pragma unroll
        for (int it = 0; it < 2; ++it) {
          gload16(Kbase + (size_t)(kvt + 64 + it * 32) * EMB, &Ks[cur ^ 1][(tid + it * 256) * 8]);
          gload16(Vbase + (size_t)(kvt + 64) + (size_t)(it * 32) * SEQ, &Vs[cur ^ 1][(tid + it * 256) * 8]);
        }
      }
      bool tilefull = (allvalid >> t) & 1;

      // QK: S^T[kv][q] seeded with -m_run (additive C-in)
      f32x4 sf[4];
      f32x4 seed = {-m_run, -m_run, -m_run, -m_run};
#pragma unroll
      for (int mf = 0; mf < 4; ++mf) sf[mf] = seed;
      __builtin_amdgcn_s_setprio(1);
#pragma unroll
      for (int s = 0; s < 2; ++s) {
#pragma unroll
        for (int mf = 0; mf < 4; ++mf) {
          bf16x8 kf = *(const bf16x8*)&Ks[cur][(mf * 16 + q) * 64 + 8 * ((4 * s + g) ^ qx7)];
          sf[mf] = __builtin_amdgcn_mfma_f32_16x16x32_bf16(kf, s ? qf1 : qf0, sf[mf], 0, 0, 0);
        }
      }
      __builtin_amdgcn_s_setprio(0);

      // mask (rare path: diagonal tile or padded tile)
      if (t == c || !tilefull) {
        unsigned long long pmask =
            tilefull ? ~0ull : __ballot(pad[b * SEQ + kvt + lane] != 0);
#pragma unroll
        for (int mf = 0; mf < 4; ++mf)
#pragma unroll
          for (int r = 0; r < 4; ++r) {
            int kvl = mf * 16 + 4 * g + r;
            bool keep = (kvt + kvl <= qg) && ((pmask >> kvl) & 1ULL);
            sf[mf][r] = keep ? sf[mf][r] : -INFINITY;
          }
      }

      // optimistic exp2 (TRANS pipe) — runs concurrently with the max tree (VALU pipe)
      float pvv[16];
#pragma unroll
      for (int mf = 0; mf < 4; ++mf)
#pragma unroll
        for (int r = 0; r < 4; ++r)
          pvv[mf * 4 + r] = __builtin_amdgcn_exp2f(sf[mf][r]);

      // lane-local max; __all over lane-local values == __all over wave max
      float t0 = fmaxf(fmaxf(sf[0][0], sf[0][1]), fmaxf(sf[0][2], sf[0][3]));
      float t1 = fmaxf(fmaxf(sf[1][0], sf[1][1]), fmaxf(sf[1][2], sf[1][3]));
      float t2 = fmaxf(fmaxf(sf[2][0], sf[2][1]), fmaxf(sf[2][2], sf[2][3]));
      float t3 = fmaxf(fmaxf(sf[3][0], sf[3][1]), fmaxf(sf[3][2], sf[3][3]));
      float tl = fmaxf(fmaxf(t0, t1), fmaxf(t2, t3));

      if (!__all(tl <= 8.0f)) {  // rare rescale path
        float tmax = fmaxf(tl, __shfl_xor(tl, 16));
        tmax = fmaxf(tmax, __shfl_xor(tmax, 32));
        float d = fmaxf(tmax, 0.f);
        float alpha = __builtin_amdgcn_exp2f(-d);
        ol[0] *= alpha;
#pragma unroll
        for (int mv = 0; mv < 4; ++mv) o[mv] *= alpha;
#pragma unroll
        for (int mf = 0; mf < 4; ++mf)
#pragma unroll
          for (int r = 0; r < 4; ++r) {
            sf[mf][r] -= d;
            pvv[mf * 4 + r] = __builtin_amdgcn_exp2f(sf[mf][r]);
          }
        m_run += d;
      }

      // pack P to bf16 and publish to per-wave LDS
#pragma unroll
      for (int mf = 0; mf < 4; ++mf) {
        uint2 w;
        w.x = cvtpk(pvv[mf * 4 + 0], pvv[mf * 4 + 1]);
        w.y = cvtpk(pvv[mf * 4 + 2], pvv[mf * 4 + 3]);
        int cbP = 2 * mf + (g >> 1);
        *(uint2*)&Ps[wave][q * 64 + 8 * (cbP ^ qx7) + 4 * (g & 1)] = w;
      }

      // PV: O^T[dv][q] += V^T[dv][kv] * P^T[kv][q]; l via ones-MFMA (column sums of P)
      __builtin_amdgcn_s_setprio(1);
#pragma unroll
      for (int s = 0; s < 2; ++s) {
        bf16x8 pb = *(const bf16x8*)&Ps[wave][q * 64 + 8 * ((4 * s + g) ^ qx7)];
#pragma unroll
        for (int mv = 0; mv < 4; ++mv) {
          bf16x8 va = *(const bf16x8*)&Vs[cur][(mv * 16 + q) * 64 + 8 * ((4 * s + g) ^ qx7)];
          o[mv] = __builtin_amdgcn_mfma_f32_16x16x32_bf16(va, pb, o[mv], 0, 0, 0);
        }
        ol = __builtin_amdgcn_mfma_f32_16x16x32_bf16(ones, pb, ol, 0, 0, 0);
      }
      __builtin_amdgcn_s_setprio(0);
      __syncthreads();  // publishes next buf, protects cur for overwrite at t+2
    }

    float inv = 1.0f / ol[0];
    unsigned short* Orow = Ob + ((size_t)(b * SEQ + qg)) * EMB + h * 64;
#pragma unroll
    for (int mv = 0; mv < 4; ++mv) {
      uint2 w;
      w.x = cvtpk(o[mv][0] * inv, o[mv][1] * inv);
      w.y = cvtpk(o[mv][2] * inv, o[mv][3] * inv);
      *(uint2*)&Orow[mv * 16 + 4 * g] = w;
    }
  }
}

extern "C" void kernel_launch(void* const* d_in, const int* in_sizes, int n_in,
                              void* d_out, int out_size, void* d_ws, size_t ws_size,
                              hipStream_t stream) {
  const float* query = (const float*)d_in[0];
  const float* key   = (const float*)d_in[1];
  const float* value = (const float*)d_in[2];
  const int*   pad   = (const int*)d_in[3];
  const float* Wq = (const float*)d_in[4];
  const float* Wk = (const float*)d_in[5];
  const float* Wv = (const float*)d_in[6];
  const float* Wo = (const float*)d_in[7];

  unsigned short* WqT = (unsigned short*)d_ws;
  unsigned short* WkT = WqT + (size_t)EMB * EMB;
  unsigned short* WvT = WkT + (size_t)EMB * EMB;
  unsigned short* WoT = WvT + (size_t)EMB * EMB;
  unsigned short* Qb  = WoT + (size_t)EMB * EMB;
  unsigned short* Kb  = Qb + (size_t)MROWS * EMB;
  unsigned short* VTb = Kb + (size_t)MROWS * EMB;
  unsigned short* Ab  = VTb + (size_t)MROWS * EMB;

  wtrans_kernel<<<dim3(EMB / 32, EMB / 32, 4), dim3(32, 8), 0, stream>>>(
      Wq, Wk, Wv, Wo, WqT, WkT, WvT, WoT);
  gemm_kernel<1, 0><<<dim3(8, 64), 256, 0, stream>>>(query, WqT, Qb);
  gemm_kernel<1, 0><<<dim3(8, 64), 256, 0, stream>>>(key, WkT, Kb);
  gemm_kernel<1, 1><<<dim3(8, 64), 256, 0, stream>>>(value, WvT, VTb);
  attn_kernel<<<dim3(1024), 256, 0, stream>>>(Qb, Kb, VTb, pad, Ab);
  gemm_kernel<0, 2><<<dim3(8, 64), 256, 0, stream>>>(Ab, WoT, (float*)d_out);
}

// Round 10
// 189.353 us; speedup vs baseline: 1.2841x; 1.0681x over previous
//
#include <hip/hip_runtime.h>
#include <hip/hip_bf16.h>

typedef short bf16x8 __attribute__((ext_vector_type(8)));
typedef float f32x4 __attribute__((ext_vector_type(4)));

#define EMB 1024
#define NH 16
#define SEQ 2048
#define BATCH 4
#define MROWS (BATCH * SEQ)

static __device__ inline unsigned short f2bf(float f) {
  unsigned u = __float_as_uint(f);
  u += 0x7fffu + ((u >> 16) & 1u);
  return (unsigned short)(u >> 16);
}

static __device__ inline unsigned cvtpk(float lo, float hi) {
  unsigned r;
  asm("v_cvt_pk_bf16_f32 %0, %1, %2" : "=v"(r) : "v"(lo), "v"(hi));
  return r;
}

static __device__ inline void gload16(const void* g, void* l) {
  __builtin_amdgcn_global_load_lds(
      (const __attribute__((address_space(1))) unsigned int*)g,
      (__attribute__((address_space(3))) unsigned int*)l, 16, 0, 0);
}

// ---------------- weight transpose + cast: W[k][n] f32 -> WT[n][k] bf16 ----------------
// z==0 (Wq) additionally folds in 0.125*log2(e) so attention logits are in exp2 domain.
__global__ __launch_bounds__(256) void wtrans_kernel(
    const float* w0, const float* w1, const float* w2, const float* w3,
    unsigned short* o0, unsigned short* o1, unsigned short* o2, unsigned short* o3) {
  __shared__ float t[32][33];
  int z = blockIdx.z;
  const float* W = z == 0 ? w0 : z == 1 ? w1 : z == 2 ? w2 : w3;
  unsigned short* O = z == 0 ? o0 : z == 1 ? o1 : z == 2 ? o2 : o3;
  float sc = (z == 0) ? 0.18033688011112042f : 1.0f;
  int bx = blockIdx.x * 32;  // k block
  int by = blockIdx.y * 32;  // n block
  int tx = threadIdx.x, ty = threadIdx.y;  // (32,8)
#pragma unroll
  for (int j = 0; j < 4; ++j)
    t[ty + j * 8][tx] = W[(size_t)(bx + ty + j * 8) * EMB + by + tx];
  __syncthreads();
#pragma unroll
  for (int j = 0; j < 4; ++j)
    O[(size_t)(by + ty + j * 8) * EMB + bx + tx] = f2bf(t[tx][ty + j * 8] * sc);
}

// ---------------- GEMM: C[M=8192][N=1024] = A[M][K=1024] * BT[N][K]^T ----------------
// IN_F32: 1 = A is f32 (cast to bf16 while staging), 0 = A is bf16 (global_load_lds)
// OUT_MODE: 0 = bf16 normal [m][n], 1 = bf16 V-transposed [b][h][dv][l], 2 = f32 [m][n]
template <int IN_F32, int OUT_MODE>
__global__ __launch_bounds__(256) void gemm_kernel(const void* Ap, const unsigned short* Bt, void* Cp) {
  __shared__ __align__(16) unsigned short As[128 * 64];  // XOR-swizzled cols
  __shared__ __align__(16) unsigned short Bs[128 * 64];
  const int K = EMB;
  int tid = threadIdx.x;
  int lane = tid & 63, wave = tid >> 6;
  int q = lane & 15, g = lane >> 4;
  int qx7 = q & 7;
  int wm = (wave >> 1) * 64, wn = (wave & 1) * 64;
  int lin = blockIdx.x + (blockIdx.y << 3);
  int idx = (lin & 7) * 64 + (lin >> 3);
  int tm = (idx >> 3) * 128, tn = (idx & 7) * 128;
  f32x4 acc[4][4] = {};
  for (int kt = 0; kt < K; kt += 64) {
    if (IN_F32) {
      const float* A = (const float*)Ap;
#pragma unroll
      for (int it = 0; it < 4; ++it) {
        int gid = tid + it * 256;
        int row = gid >> 3, cb = gid & 7;
        const float4* s0 = (const float4*)(A + (size_t)(tm + row) * K + kt + cb * 8);
        float4 x = s0[0], y = s0[1];
        uint4 w;
        w.x = cvtpk(x.x, x.y); w.y = cvtpk(x.z, x.w);
        w.z = cvtpk(y.x, y.y); w.w = cvtpk(y.z, y.w);
        *(uint4*)&As[row * 64 + 8 * (cb ^ (row & 7))] = w;
      }
    } else {
      const unsigned short* A = (const unsigned short*)Ap;
#pragma unroll
      for (int it = 0; it < 4; ++it) {
        int gid = tid + it * 256;
        int row = gid >> 3, cb = gid & 7;
        gload16(A + (size_t)(tm + row) * K + kt + 8 * (cb ^ (row & 7)), &As[gid * 8]);
      }
    }
#pragma unroll
    for (int it = 0; it < 4; ++it) {
      int gid = tid + it * 256;
      int row = gid >> 3, cb = gid & 7;
      gload16(Bt + (size_t)(tn + row) * K + kt + 8 * (cb ^ (row & 7)), &Bs[gid * 8]);
    }
    __syncthreads();
#pragma unroll
    for (int s = 0; s < 2; ++s) {
      bf16x8 af[4], bfr[4];
#pragma unroll
      for (int mf = 0; mf < 4; ++mf)
        af[mf] = *(const bf16x8*)&As[(wm + mf * 16 + q) * 64 + 8 * ((4 * s + g) ^ qx7)];
#pragma unroll
      for (int nf = 0; nf < 4; ++nf)
        bfr[nf] = *(const bf16x8*)&Bs[(wn + nf * 16 + q) * 64 + 8 * ((4 * s + g) ^ qx7)];
#pragma unroll
      for (int mf = 0; mf < 4; ++mf)
#pragma unroll
        for (int nf = 0; nf < 4; ++nf)
          acc[mf][nf] = __builtin_amdgcn_mfma_f32_16x16x32_bf16(af[mf], bfr[nf], acc[mf][nf], 0, 0, 0);
    }
    __syncthreads();
  }
  if (OUT_MODE == 0) {
    unsigned short* C = (unsigned short*)Cp;
#pragma unroll
    for (int mf = 0; mf < 4; ++mf)
#pragma unroll
      for (int nf = 0; nf < 4; ++nf)
#pragma unroll
        for (int r = 0; r < 4; ++r) {
          int row = tm + wm + mf * 16 + 4 * g + r;
          int col = tn + wn + nf * 16 + q;
          C[(size_t)row * EMB + col] = f2bf(acc[mf][nf][r]);
        }
  } else if (OUT_MODE == 1) {
    unsigned short* C = (unsigned short*)Cp;
#pragma unroll
    for (int mf = 0; mf < 4; ++mf) {
      int m0 = tm + wm + mf * 16 + 4 * g;
      int b = m0 >> 11, l = m0 & 2047;
#pragma unroll
      for (int nf = 0; nf < 4; ++nf) {
        int n = tn + wn + nf * 16 + q;
        int h = n >> 6, dv = n & 63;
        uint2 w;
        w.x = cvtpk(acc[mf][nf][0], acc[mf][nf][1]);
        w.y = cvtpk(acc[mf][nf][2], acc[mf][nf][3]);
        *(uint2*)&C[(((size_t)b * NH + h) * 64 + dv) * SEQ + l] = w;
      }
    }
  } else {
    float* C = (float*)Cp;
#pragma unroll
    for (int mf = 0; mf < 4; ++mf)
#pragma unroll
      for (int nf = 0; nf < 4; ++nf)
#pragma unroll
        for (int r = 0; r < 4; ++r) {
          int row = tm + wm + mf * 16 + 4 * g + r;
          int col = tn + wn + nf * 16 + q;
          C[(size_t)row * EMB + col] = acc[mf][nf][r];
        }
  }
}

// ---------------- flash attention: 128 q-rows/block, R8-exact per-block softmax ----------------
// Q,K bf16 [b][l][h*64+d] (Q pre-scaled by 0.125*log2e); VT bf16 [b][h][dv][l]; out bf16.
// 4 waves x 32 q rows (two 16-col blocks A,B); K/V fragments read once, feed both blocks.
// Softmax per column-block is byte-identical to the validated R8 path (separate triggers,
// exp2 into pvv, pack after rescale decision). LDS 48KB -> 3 blocks/CU.
__global__ __launch_bounds__(256) void attn_kernel(
    const unsigned short* Qb, const unsigned short* Kb, const unsigned short* VTb,
    const int* pad, unsigned short* Ob) {
  __shared__ __align__(16) unsigned short Ks[2][64 * 64];   // [kv][d], src-XOR-swizzled
  __shared__ __align__(16) unsigned short Vs[2][64 * 64];   // [dv][kv], src-XOR-swizzled
  __shared__ __align__(16) unsigned short Ps[4][32 * 64];   // per-wave P, XOR-swizzled
  int tid = threadIdx.x;
  int lane = tid & 63, wave = tid >> 6;
  int q = lane & 15, g = lane >> 4;
  int qx7 = q & 7;
  // XCD-chunked swizzle: 512 blocks, 64/XCD
  int lin = blockIdx.x;
  int idx = (lin & 7) * 64 + (lin >> 3);
  int b = idx >> 7, h = (idx >> 3) & 15, px = idx & 7;

  // per-tile "fully valid" bitmask, wave-uniform. Rare non-full tiles re-ballot inline.
  unsigned allvalid = 0;
#pragma unroll 8
  for (int t0 = 0; t0 < 32; ++t0) {
    int pv = pad[b * SEQ + t0 * 64 + lane];
    if (__ballot(pv != 0) == ~0ull) allvalid |= (1u << t0);
  }

  bf16x8 ones;
#pragma unroll
  for (int i = 0; i < 8; ++i) ones[i] = (short)0x3F80;  // bf16 1.0

  int srow = tid >> 3, scb = tid & 7;
  int ssw = 8 * (scb ^ (srow & 7));
  const unsigned short* Kbase = Kb + (size_t)b * SEQ * EMB + (size_t)srow * EMB + h * 64 + ssw;
  const unsigned short* Vbase = VTb + (((size_t)(b * NH + h)) * 64 + srow) * SEQ + ssw;

#pragma unroll 1
  for (int half = 0; half < 2; ++half) {
    int c = half ? 15 - px : px;
    int tend = 2 * c + 1;                // last kv tile index for this 128-row chunk
    int qbase = c * 128 + wave * 32;     // this wave's 32 q rows
    int qgA = qbase + q;                 // column block A rows
    int qgB = qbase + 16 + q;            // column block B rows
    const unsigned short* QrowA = Qb + ((size_t)(b * SEQ + qgA)) * EMB + h * 64;
    const unsigned short* QrowB = Qb + ((size_t)(b * SEQ + qgB)) * EMB + h * 64;
    bf16x8 qA0 = *(const bf16x8*)(QrowA + 8 * g);
    bf16x8 qA1 = *(const bf16x8*)(QrowA + 32 + 8 * g);
    bf16x8 qB0 = *(const bf16x8*)(QrowB + 8 * g);
    bf16x8 qB1 = *(const bf16x8*)(QrowB + 32 + 8 * g);

    f32x4 oA[4] = {}, oB[4] = {};
    f32x4 olA = {}, olB = {};
    float mA = 0.f, mB = 0.f;

    // prologue: stage tile 0 into buf 0
#pragma unroll
    for (int it = 0; it < 2; ++it) {
      gload16(Kbase + (size_t)(it * 32) * EMB, &Ks[0][(tid + it * 256) * 8]);
      gload16(Vbase + (size_t)(it * 32) * SEQ, &Vs[0][(tid + it * 256) * 8]);
    }
    __syncthreads();

#pragma unroll 1
    for (int t = 0; t <= tend; ++t) {
      int kvt = t * 64;
      int cur = t & 1;
      if (t < tend) {
#pragma unroll
        for (int it = 0; it < 2; ++it) {
          gload16(Kbase + (size_t)(kvt + 64 + it * 32) * EMB, &Ks[cur ^ 1][(tid + it * 256) * 8]);
          gload16(Vbase + (size_t)(kvt + 64) + (size_t)(it * 32) * SEQ, &Vs[cur ^ 1][(tid + it * 256) * 8]);
        }
      }
      bool active = (kvt < qbase + 32);  // wave-uniform: skip fully-above-diagonal tiles
      if (active) {
        bool tilefull = (allvalid >> t) & 1;

        // QK for both column blocks; K fragments read once, used twice
        f32x4 sA[4], sB[4];
        f32x4 seedA = {-mA, -mA, -mA, -mA};
        f32x4 seedB = {-mB, -mB, -mB, -mB};
#pragma unroll
        for (int mf = 0; mf < 4; ++mf) { sA[mf] = seedA; sB[mf] = seedB; }
        __builtin_amdgcn_s_setprio(1);
#pragma unroll
        for (int s = 0; s < 2; ++s) {
#pragma unroll
          for (int mf = 0; mf < 4; ++mf) {
            bf16x8 kf = *(const bf16x8*)&Ks[cur][(mf * 16 + q) * 64 + 8 * ((4 * s + g) ^ qx7)];
            sA[mf] = __builtin_amdgcn_mfma_f32_16x16x32_bf16(kf, s ? qA1 : qA0, sA[mf], 0, 0, 0);
            sB[mf] = __builtin_amdgcn_mfma_f32_16x16x32_bf16(kf, s ? qB1 : qB0, sB[mf], 0, 0, 0);
          }
        }
        __builtin_amdgcn_s_setprio(0);

        // mask (diagonal or padded tiles only; for active tiles kvt <= qbase always)
        if ((kvt + 63 > qbase) || !tilefull) {
          unsigned long long pmask =
              tilefull ? ~0ull : __ballot(pad[b * SEQ + kvt + lane] != 0);
#pragma unroll
          for (int mf = 0; mf < 4; ++mf)
#pragma unroll
            for (int r = 0; r < 4; ++r) {
              int kvl = mf * 16 + 4 * g + r;
              int kvg = kvt + kvl;
              bool bit = (pmask >> kvl) & 1ULL;
              sA[mf][r] = (kvg <= qgA && bit) ? sA[mf][r] : -INFINITY;
              sB[mf][r] = (kvg <= qgB && bit) ? sB[mf][r] : -INFINITY;
            }
        }

        // ---- softmax block A (R8-exact) ----
        {
          float pvv[16];
#pragma unroll
          for (int mf = 0; mf < 4; ++mf)
#pragma unroll
            for (int r = 0; r < 4; ++r)
              pvv[mf * 4 + r] = __builtin_amdgcn_exp2f(sA[mf][r]);
          float t0 = fmaxf(fmaxf(sA[0][0], sA[0][1]), fmaxf(sA[0][2], sA[0][3]));
          float t1 = fmaxf(fmaxf(sA[1][0], sA[1][1]), fmaxf(sA[1][2], sA[1][3]));
          float t2 = fmaxf(fmaxf(sA[2][0], sA[2][1]), fmaxf(sA[2][2], sA[2][3]));
          float t3 = fmaxf(fmaxf(sA[3][0], sA[3][1]), fmaxf(sA[3][2], sA[3][3]));
          float tl = fmaxf(fmaxf(t0, t1), fmaxf(t2, t3));
          if (!__all(tl <= 8.0f)) {
            float tmax = fmaxf(tl, __shfl_xor(tl, 16));
            tmax = fmaxf(tmax, __shfl_xor(tmax, 32));
            float d = fmaxf(tmax, 0.f);
            float alpha = __builtin_amdgcn_exp2f(-d);
            olA *= alpha;
#pragma unroll
            for (int mv = 0; mv < 4; ++mv) oA[mv] *= alpha;
#pragma unroll
            for (int mf = 0; mf < 4; ++mf)
#pragma unroll
              for (int r = 0; r < 4; ++r) {
                sA[mf][r] -= d;
                pvv[mf * 4 + r] = __builtin_amdgcn_exp2f(sA[mf][r]);
              }
            mA += d;
          }
#pragma unroll
          for (int mf = 0; mf < 4; ++mf) {
            uint2 w;
            w.x = cvtpk(pvv[mf * 4 + 0], pvv[mf * 4 + 1]);
            w.y = cvtpk(pvv[mf * 4 + 2], pvv[mf * 4 + 3]);
            int cbP = 2 * mf + (g >> 1);
            *(uint2*)&Ps[wave][q * 64 + 8 * (cbP ^ qx7) + 4 * (g & 1)] = w;
          }
        }
        // ---- softmax block B (R8-exact) ----
        {
          float pvv[16];
#pragma unroll
          for (int mf = 0; mf < 4; ++mf)
#pragma unroll
            for (int r = 0; r < 4; ++r)
              pvv[mf * 4 + r] = __builtin_amdgcn_exp2f(sB[mf][r]);
          float t0 = fmaxf(fmaxf(sB[0][0], sB[0][1]), fmaxf(sB[0][2], sB[0][3]));
          float t1 = fmaxf(fmaxf(sB[1][0], sB[1][1]), fmaxf(sB[1][2], sB[1][3]));
          float t2 = fmaxf(fmaxf(sB[2][0], sB[2][1]), fmaxf(sB[2][2], sB[2][3]));
          float t3 = fmaxf(fmaxf(sB[3][0], sB[3][1]), fmaxf(sB[3][2], sB[3][3]));
          float tl = fmaxf(fmaxf(t0, t1), fmaxf(t2, t3));
          if (!__all(tl <= 8.0f)) {
            float tmax = fmaxf(tl, __shfl_xor(tl, 16));
            tmax = fmaxf(tmax, __shfl_xor(tmax, 32));
            float d = fmaxf(tmax, 0.f);
            float alpha = __builtin_amdgcn_exp2f(-d);
            olB *= alpha;
#pragma unroll
            for (int mv = 0; mv < 4; ++mv) oB[mv] *= alpha;
#pragma unroll
            for (int mf = 0; mf < 4; ++mf)
#pragma unroll
              for (int r = 0; r < 4; ++r) {
                sB[mf][r] -= d;
                pvv[mf * 4 + r] = __builtin_amdgcn_exp2f(sB[mf][r]);
              }
            mB += d;
          }
#pragma unroll
          for (int mf = 0; mf < 4; ++mf) {
            uint2 w;
            w.x = cvtpk(pvv[mf * 4 + 0], pvv[mf * 4 + 1]);
            w.y = cvtpk(pvv[mf * 4 + 2], pvv[mf * 4 + 3]);
            int cbP = 2 * mf + (g >> 1);
            *(uint2*)&Ps[wave][(16 + q) * 64 + 8 * (cbP ^ qx7) + 4 * (g & 1)] = w;
          }
        }

        // PV: V fragments read once, used for both column blocks; l via ones-MFMA
        __builtin_amdgcn_s_setprio(1);
#pragma unroll
        for (int s = 0; s < 2; ++s) {
          bf16x8 pbA = *(const bf16x8*)&Ps[wave][q * 64 + 8 * ((4 * s + g) ^ qx7)];
          bf16x8 pbB = *(const bf16x8*)&Ps[wave][(16 + q) * 64 + 8 * ((4 * s + g) ^ qx7)];
#pragma unroll
          for (int mv = 0; mv < 4; ++mv) {
            bf16x8 va = *(const bf16x8*)&Vs[cur][(mv * 16 + q) * 64 + 8 * ((4 * s + g) ^ qx7)];
            oA[mv] = __builtin_amdgcn_mfma_f32_16x16x32_bf16(va, pbA, oA[mv], 0, 0, 0);
            oB[mv] = __builtin_amdgcn_mfma_f32_16x16x32_bf16(va, pbB, oB[mv], 0, 0, 0);
          }
          olA = __builtin_amdgcn_mfma_f32_16x16x32_bf16(ones, pbA, olA, 0, 0, 0);
          olB = __builtin_amdgcn_mfma_f32_16x16x32_bf16(ones, pbB, olB, 0, 0, 0);
        }
        __builtin_amdgcn_s_setprio(0);
      }
      __syncthreads();  // publishes next buf, protects cur for overwrite at t+2
    }

    float invA = 1.0f / olA[0];
    float invB = 1.0f / olB[0];
    unsigned short* OrowA = Ob + ((size_t)(b * SEQ + qgA)) * EMB + h * 64;
    unsigned short* OrowB = Ob + ((size_t)(b * SEQ + qgB)) * EMB + h * 64;
#pragma unroll
    for (int mv = 0; mv < 4; ++mv) {
      uint2 wa, wb;
      wa.x = cvtpk(oA[mv][0] * invA, oA[mv][1] * invA);
      wa.y = cvtpk(oA[mv][2] * invA, oA[mv][3] * invA);
      wb.x = cvtpk(oB[mv][0] * invB, oB[mv][1] * invB);
      wb.y = cvtpk(oB[mv][2] * invB, oB[mv][3] * invB);
      *(uint2*)&OrowA[mv * 16 + 4 * g] = wa;
      *(uint2*)&OrowB[mv * 16 + 4 * g] = wb;
    }
  }
}

extern "C" void kernel_launch(void* const* d_in, const int* in_sizes, int n_in,
                              void* d_out, int out_size, void* d_ws, size_t ws_size,
                              hipStream_t stream) {
  const float* query = (const float*)d_in[0];
  const float* key   = (const float*)d_in[1];
  const float* value = (const float*)d_in[2];
  const int*   pad   = (const int*)d_in[3];
  const float* Wq = (const float*)d_in[4];
  const float* Wk = (const float*)d_in[5];
  const float* Wv = (const float*)d_in[6];
  const float* Wo = (const float*)d_in[7];

  unsigned short* WqT = (unsigned short*)d_ws;
  unsigned short* WkT = WqT + (size_t)EMB * EMB;
  unsigned short* WvT = WkT + (size_t)EMB * EMB;
  unsigned short* WoT = WvT + (size_t)EMB * EMB;
  unsigned short* Qb  = WoT + (size_t)EMB * EMB;
  unsigned short* Kb  = Qb + (size_t)MROWS * EMB;
  unsigned short* VTb = Kb + (size_t)MROWS * EMB;
  unsigned short* Ab  = VTb + (size_t)MROWS * EMB;

  wtrans_kernel<<<dim3(EMB / 32, EMB / 32, 4), dim3(32, 8), 0, stream>>>(
      Wq, Wk, Wv, Wo, WqT, WkT, WvT, WoT);
  gemm_kernel<1, 0><<<dim3(8, 64), 256, 0, stream>>>(query, WqT, Qb);
  gemm_kernel<1, 0><<<dim3(8, 64), 256, 0, stream>>>(key, WkT, Kb);
  gemm_kernel<1, 1><<<dim3(8, 64), 256, 0, stream>>>(value, WvT, VTb);
  attn_kernel<<<dim3(512), 256, 0, stream>>>(Qb, Kb, VTb, pad, Ab);
  gemm_kernel<0, 2><<<dim3(8, 64), 256, 0, stream>>>(Ab, WoT, (float*)d_out);
}